// Round 9
// baseline (1133.477 us; speedup 1.0000x reference)
//
#include <hip/hip_runtime.h>
#include <cmath>

// DenseRnn on MI355X. Shapes: B=2, N=2048, D=1024, H=8, HD=128.
//
//  1. wtrans_split: Wq/Wk/Wv fp32 [K][N] -> bf16 hi+lo WT [N][K]; Wo -> plain bf16 WT
//     conv_split: x -> bf16 hi+lo;  wcat: [Wf1|Wog1] -> [1024][256]
//  2. gemm_bf16_split (MFMA 16x16x32, 3-term bf16x2): qraw/kraw/vraw = x@W, ~fp32 accuracy
//  3. gemm_f32 x@Wcat -> f1og [4096][256] (f1 cols 0-127, og1 cols 128-255)
//  4. prep: silu/l2norm/beta/e; record sb[row*8+h][520] = {k,e,qe,v, sc@512}
//  5. scan: 16 lanes/col x 8 rows/lane (4 cols/wave -> broadcast dedup),
//     pure-DPP 16-lane reductions (no ds_swizzle), ke computed in-reg,
//     16-token double-buffered LDS ring staged via global_load_lds.
//  6. post: gate, sigmoid, per-head RMS, *norm_w -> bf16 y
//  7. gemm_bf16 y@Wo -> out
//
// R8 post-mortem: scan was LDS-instruction-throughput-bound (36 LDS ops/CU/token).
// This geometry cuts it to 16/token with zero swizzles.

#define SZT ((size_t)4096 * 1024)
#define RECF 520
#define RECSTRIDE 4160     // 8*RECF floats between consecutive tokens of a stream
#define TOKB 16            // tokens per staged batch
#define SLOTB 1600         // LDS bytes/slot: k 512 | e 512 | qe 512 | v 32 | sc 16 | pad

typedef unsigned short u16;
typedef __attribute__((ext_vector_type(8))) short short8;
typedef __attribute__((ext_vector_type(4))) float f32x4;

__device__ __forceinline__ float sigmf(float x) { return 1.f / (1.f + expf(-x)); }
__device__ __forceinline__ float siluf(float x) { return x * sigmf(x); }
__device__ __forceinline__ u16 f2bf(float f) {
    unsigned int u = __float_as_uint(f);
    unsigned int r = (u + 0x7FFFu + ((u >> 16) & 1u)) >> 16;
    return (u16)r;
}
__device__ __forceinline__ float bf2f(u16 h) { return __uint_as_float((unsigned int)h << 16); }
__device__ __forceinline__ void splitbf(float f, u16& hi, u16& lo) {
    hi = f2bf(f);
    lo = f2bf(f - bf2f(hi));
}

#define GLOAD_LDS16(gp, lp) __builtin_amdgcn_global_load_lds( \
    (const __attribute__((address_space(1))) void*)(gp),      \
    (__attribute__((address_space(3))) void*)(lp), 16, 0, 0)

// ---------------- transpose+convert (split): W fp32 [1024][1024] -> hi/lo bf16 [N][K]
__global__ __launch_bounds__(256) void wtrans_split(
    const float* __restrict__ W, u16* __restrict__ WTh, u16* __restrict__ WTl)
{
    __shared__ float t[32][33];
    const int tx = threadIdx.x & 31, ty = threadIdx.x >> 5;
    const int n0 = blockIdx.x * 32, k0 = blockIdx.y * 32;
#pragma unroll
    for (int i = 0; i < 4; i++)
        t[ty + i * 8][tx] = W[(size_t)(k0 + ty + i * 8) * 1024 + n0 + tx];
    __syncthreads();
#pragma unroll
    for (int i = 0; i < 4; i++) {
        u16 hi, lo;
        splitbf(t[tx][ty + i * 8], hi, lo);
        WTh[(size_t)(n0 + ty + i * 8) * 1024 + k0 + tx] = hi;
        WTl[(size_t)(n0 + ty + i * 8) * 1024 + k0 + tx] = lo;
    }
}

// ---------------- transpose+convert (plain)
__global__ __launch_bounds__(256) void wtrans(const float* __restrict__ W, u16* __restrict__ WT)
{
    __shared__ float t[32][33];
    const int tx = threadIdx.x & 31, ty = threadIdx.x >> 5;
    const int n0 = blockIdx.x * 32, k0 = blockIdx.y * 32;
#pragma unroll
    for (int i = 0; i < 4; i++)
        t[ty + i * 8][tx] = W[(size_t)(k0 + ty + i * 8) * 1024 + n0 + tx];
    __syncthreads();
#pragma unroll
    for (int i = 0; i < 4; i++)
        WT[(size_t)(n0 + ty + i * 8) * 1024 + k0 + tx] = f2bf(t[tx][ty + i * 8]);
}

// ---------------- fp32 -> bf16 hi/lo elementwise
__global__ __launch_bounds__(256) void conv_split(
    const float* __restrict__ in, u16* __restrict__ oh, u16* __restrict__ ol)
{
    const size_t i = ((size_t)blockIdx.x * 256 + threadIdx.x) * 8;
    short8 rh, rl;
#pragma unroll
    for (int j = 0; j < 8; j++) {
        u16 hi, lo;
        splitbf(in[i + j], hi, lo);
        rh[j] = (short)hi; rl[j] = (short)lo;
    }
    *(short8*)&oh[i] = rh;
    *(short8*)&ol[i] = rl;
}

// ---------------- concat Wf1|Wog1 -> Wcat [1024][256]
__global__ __launch_bounds__(256) void wcat_kernel(
    const float* __restrict__ Wf1, const float* __restrict__ Wog1, float* __restrict__ Wcat)
{
    const int idx = blockIdx.x * 256 + threadIdx.x;   // 0..262143
    const int k = idx >> 8, j = idx & 255;
    Wcat[idx] = (j < 128) ? Wf1[k * 128 + j] : Wog1[k * 128 + j - 128];
}

// ---------------- split bf16 MFMA GEMM: C = (Ah+Al) @ (BTh+BTl)^T (3-term), fp32 out.
__global__ __launch_bounds__(256) void gemm_bf16_split(
    const u16* __restrict__ Ah, const u16* __restrict__ Al,
    const u16* __restrict__ BTh, const u16* __restrict__ BTl,
    float* __restrict__ C, int M, int N, int K)
{
    __shared__ u16 AsH[128 * 32];
    __shared__ u16 AsL[128 * 32];
    __shared__ u16 BsH[128 * 32];
    __shared__ u16 BsL[128 * 32];
    const int tid = threadIdx.x;
    const int lane = tid & 63;
    const int w = tid >> 6;
    const int wr = w >> 1, wc = w & 1;
    const int row0 = blockIdx.y * 128;
    const int col0 = blockIdx.x * 128;
    const int mrow = lane & 15;
    const int kgrp = (lane >> 4) * 8;

    f32x4 acc[4][4] = {};

    const int off0 = w * 1024 + lane * 16;
    const int r0 = off0 >> 6, kl0 = (off0 & 63) >> 1;
    const int off1 = off0 + 4096;
    const int r1 = off1 >> 6, kl1 = (off1 & 63) >> 1;

    for (int kt = 0; kt < K; kt += 32) {
        GLOAD_LDS16(Ah  + (size_t)(row0 + r0) * K + kt + kl0, (char*)AsH + w * 1024);
        GLOAD_LDS16(Ah  + (size_t)(row0 + r1) * K + kt + kl1, (char*)AsH + w * 1024 + 4096);
        GLOAD_LDS16(Al  + (size_t)(row0 + r0) * K + kt + kl0, (char*)AsL + w * 1024);
        GLOAD_LDS16(Al  + (size_t)(row0 + r1) * K + kt + kl1, (char*)AsL + w * 1024 + 4096);
        GLOAD_LDS16(BTh + (size_t)(col0 + r0) * K + kt + kl0, (char*)BsH + w * 1024);
        GLOAD_LDS16(BTh + (size_t)(col0 + r1) * K + kt + kl1, (char*)BsH + w * 1024 + 4096);
        GLOAD_LDS16(BTl + (size_t)(col0 + r0) * K + kt + kl0, (char*)BsL + w * 1024);
        GLOAD_LDS16(BTl + (size_t)(col0 + r1) * K + kt + kl1, (char*)BsL + w * 1024 + 4096);
        __syncthreads();

        short8 aH[4], aL[4], bH[4], bL[4];
#pragma unroll
        for (int mi = 0; mi < 4; ++mi) {
            aH[mi] = *(const short8*)&AsH[(wr * 64 + mi * 16 + mrow) * 32 + kgrp];
            aL[mi] = *(const short8*)&AsL[(wr * 64 + mi * 16 + mrow) * 32 + kgrp];
        }
#pragma unroll
        for (int ni = 0; ni < 4; ++ni) {
            bH[ni] = *(const short8*)&BsH[(wc * 64 + ni * 16 + mrow) * 32 + kgrp];
            bL[ni] = *(const short8*)&BsL[(wc * 64 + ni * 16 + mrow) * 32 + kgrp];
        }
#pragma unroll
        for (int mi = 0; mi < 4; ++mi)
#pragma unroll
            for (int ni = 0; ni < 4; ++ni) {
                acc[mi][ni] = __builtin_amdgcn_mfma_f32_16x16x32_bf16(aH[mi], bH[ni], acc[mi][ni], 0, 0, 0);
                acc[mi][ni] = __builtin_amdgcn_mfma_f32_16x16x32_bf16(aL[mi], bH[ni], acc[mi][ni], 0, 0, 0);
                acc[mi][ni] = __builtin_amdgcn_mfma_f32_16x16x32_bf16(aH[mi], bL[ni], acc[mi][ni], 0, 0, 0);
            }
        __syncthreads();
    }

    const int crow = (lane >> 4) * 4;
#pragma unroll
    for (int mi = 0; mi < 4; ++mi)
#pragma unroll
        for (int ni = 0; ni < 4; ++ni)
#pragma unroll
            for (int j = 0; j < 4; ++j)
                C[(size_t)(row0 + wr * 64 + mi * 16 + crow + j) * N + col0 + wc * 64 + ni * 16 + mrow]
                    = acc[mi][ni][j];
}

// ---------------- plain bf16 MFMA GEMM (final projection)
__global__ __launch_bounds__(256) void gemm_bf16(
    const u16* __restrict__ A, const u16* __restrict__ BT, float* __restrict__ C,
    int M, int N, int K)
{
    __shared__ u16 As[128 * 32];
    __shared__ u16 Bs[128 * 32];
    const int tid = threadIdx.x;
    const int lane = tid & 63;
    const int w = tid >> 6;
    const int wr = w >> 1, wc = w & 1;
    const int row0 = blockIdx.y * 128;
    const int col0 = blockIdx.x * 128;
    const int mrow = lane & 15;
    const int kgrp = (lane >> 4) * 8;

    f32x4 acc[4][4] = {};

    const int off0 = w * 1024 + lane * 16;
    const int r0 = off0 >> 6, kl0 = (off0 & 63) >> 1;
    const int off1 = off0 + 4096;
    const int r1 = off1 >> 6, kl1 = (off1 & 63) >> 1;

    for (int kt = 0; kt < K; kt += 32) {
        GLOAD_LDS16(A  + (size_t)(row0 + r0) * K + kt + kl0, (char*)As + w * 1024);
        GLOAD_LDS16(A  + (size_t)(row0 + r1) * K + kt + kl1, (char*)As + w * 1024 + 4096);
        GLOAD_LDS16(BT + (size_t)(col0 + r0) * K + kt + kl0, (char*)Bs + w * 1024);
        GLOAD_LDS16(BT + (size_t)(col0 + r1) * K + kt + kl1, (char*)Bs + w * 1024 + 4096);
        __syncthreads();

        short8 aF[4], bF[4];
#pragma unroll
        for (int mi = 0; mi < 4; ++mi)
            aF[mi] = *(const short8*)&As[(wr * 64 + mi * 16 + mrow) * 32 + kgrp];
#pragma unroll
        for (int ni = 0; ni < 4; ++ni)
            bF[ni] = *(const short8*)&Bs[(wc * 64 + ni * 16 + mrow) * 32 + kgrp];
#pragma unroll
        for (int mi = 0; mi < 4; ++mi)
#pragma unroll
            for (int ni = 0; ni < 4; ++ni)
                acc[mi][ni] = __builtin_amdgcn_mfma_f32_16x16x32_bf16(aF[mi], bF[ni], acc[mi][ni], 0, 0, 0);
        __syncthreads();
    }

    const int crow = (lane >> 4) * 4;
#pragma unroll
    for (int mi = 0; mi < 4; ++mi)
#pragma unroll
        for (int ni = 0; ni < 4; ++ni)
#pragma unroll
            for (int j = 0; j < 4; ++j)
                C[(size_t)(row0 + wr * 64 + mi * 16 + crow + j) * N + col0 + wc * 64 + ni * 16 + mrow]
                    = acc[mi][ni][j];
}

// ---------------- fp32 GEMM (fused low-rank path, N=256)
__global__ __launch_bounds__(256) void gemm_f32(
    const float* __restrict__ A, const float* __restrict__ B, float* __restrict__ C,
    int M, int N, int K)
{
    __shared__ float As[16][64];
    __shared__ float Bs[16][64];
    const int tid = threadIdx.x;
    const int row0 = blockIdx.y * 64;
    const int col0 = blockIdx.x * 64;
    const int tx = tid & 15, ty = tid >> 4;
    const int am = tid >> 2, akc = tid & 3;
    const int bkr = tid >> 4, bnc = tid & 15;

    float acc[4][4];
#pragma unroll
    for (int i = 0; i < 4; i++)
#pragma unroll
        for (int j = 0; j < 4; j++) acc[i][j] = 0.f;

    for (int k0 = 0; k0 < K; k0 += 16) {
        float4 av = *(const float4*)&A[(size_t)(row0 + am) * K + k0 + akc * 4];
        float4 bv = *(const float4*)&B[(size_t)(k0 + bkr) * N + col0 + bnc * 4];
        As[akc * 4 + 0][am] = av.x;
        As[akc * 4 + 1][am] = av.y;
        As[akc * 4 + 2][am] = av.z;
        As[akc * 4 + 3][am] = av.w;
        *(float4*)&Bs[bkr][bnc * 4] = bv;
        __syncthreads();
#pragma unroll
        for (int kk = 0; kk < 16; kk++) {
            float4 a = *(const float4*)&As[kk][ty * 4];
            float4 b = *(const float4*)&Bs[kk][tx * 4];
            acc[0][0] += a.x * b.x; acc[0][1] += a.x * b.y; acc[0][2] += a.x * b.z; acc[0][3] += a.x * b.w;
            acc[1][0] += a.y * b.x; acc[1][1] += a.y * b.y; acc[1][2] += a.y * b.z; acc[1][3] += a.y * b.w;
            acc[2][0] += a.z * b.x; acc[2][1] += a.z * b.y; acc[2][2] += a.z * b.z; acc[2][3] += a.z * b.w;
            acc[3][0] += a.w * b.x; acc[3][1] += a.w * b.y; acc[3][2] += a.w * b.z; acc[3][3] += a.w * b.w;
        }
        __syncthreads();
    }
#pragma unroll
    for (int i = 0; i < 4; i++) {
        float4 o = make_float4(acc[i][0], acc[i][1], acc[i][2], acc[i][3]);
        *(float4*)&C[(size_t)(row0 + ty * 4 + i) * N + col0 + tx * 4] = o;
    }
}

// ---------------- prep: one block per (row, h), 128 threads.
// Record: {k[128] @0, e[128] @128, qe[128] @256, v[128] @384, sc[4] @512} (RECF=520)
__global__ __launch_bounds__(128) void prep_kernel(
    const float* __restrict__ x, const float* __restrict__ Wbeta,
    const float* __restrict__ Wf2, const float* __restrict__ f1og,
    const float* __restrict__ qraw, const float* __restrict__ kraw,
    const float* __restrict__ vraw, float* __restrict__ sb)
{
    const int gid = blockIdx.x;
    const int h = gid & 7;
    const int row = gid >> 3;
    const int tid = threadIdx.x;
    const int col = h * 128 + tid;
    const size_t rbase = (size_t)row * 1024;

    __shared__ float f1s[128];
    __shared__ float red[3][128];

    f1s[tid] = f1og[(size_t)row * 256 + tid];

    float bsum = 0.f;
#pragma unroll
    for (int i = 0; i < 8; i++)
        bsum += x[rbase + tid + i * 128] * Wbeta[(size_t)(tid + i * 128) * 8 + h];

    float kr = kraw[rbase + col];
    float ksil = siluf(kr);

    red[0][tid] = bsum;
    red[1][tid] = ksil * ksil;
    __syncthreads();

    float fsum = 0.f;
#pragma unroll 8
    for (int i = 0; i < 128; i++) fsum += f1s[i] * Wf2[(size_t)i * 1024 + col];

    for (int off = 64; off > 0; off >>= 1) {
        if (tid < off) {
            red[0][tid] += red[0][tid + off];
            red[1][tid] += red[1][tid + off];
        }
        __syncthreads();
    }
    const float beta = 2.f * sigmf(red[0][0]);
    const float rn = rsqrtf(red[1][0] + 1e-6f);
    __syncthreads();

    const float kn = ksil * rn;
    const float e  = sigmf(fsum);
    const float qs = siluf(qraw[rbase + col]);
    const float vs = siluf(vraw[rbase + col]);
    const float kev = e * kn;
    const float qev = e * qs;

    red[0][tid] = kev * kn;   // -> c  = sum(e k^2)
    red[1][tid] = qs * kev;   // -> d1 = sum(q e k)
    red[2][tid] = qs * kn;    // -> d2 = sum(q k)
    __syncthreads();
    for (int off = 64; off > 0; off >>= 1) {
        if (tid < off) {
            red[0][tid] += red[0][tid + off];
            red[1][tid] += red[1][tid + off];
            red[2][tid] += red[2][tid + off];
        }
        __syncthreads();
    }

    float* o = sb + (size_t)gid * RECF;
    o[tid]        = kn;
    o[128 + tid]  = e;
    o[256 + tid]  = qev;
    o[384 + tid]  = vs;
    if (tid == 0) {
        o[512] = beta;
        o[513] = red[0][0];
        o[514] = red[1][0];
        o[515] = red[2][0];
    }
}

// ---------------- scan
// 16-lane sum, pure DPP (VALU pipe only; columns are 16-lane-aligned groups).
__device__ __forceinline__ float red16(float x)
{
    x += __int_as_float(__builtin_amdgcn_mov_dpp(__float_as_int(x), 0xB1,  0xF, 0xF, true)); // quad xor1
    x += __int_as_float(__builtin_amdgcn_mov_dpp(__float_as_int(x), 0x4E,  0xF, 0xF, true)); // quad xor2
    x += __int_as_float(__builtin_amdgcn_mov_dpp(__float_as_int(x), 0x141, 0xF, 0xF, true)); // row_half_mirror
    x += __int_as_float(__builtin_amdgcn_mov_dpp(__float_as_int(x), 0x140, 0xF, 0xF, true)); // row_mirror
    return x;
}

// Stage TOKB records via global_load_lds (per-lane global src; linear LDS dest).
// Wave w (of 2) stages slots s == w (mod 2).
__device__ __forceinline__ void stage_batch(
    const float* __restrict__ p0, char* ldsbuf, int t0, int w, int lane, int cg)
{
    for (int s = w; s < TOKB; s += 2) {
        const char* src = (const char*)(p0 + (size_t)(t0 + s) * RECSTRIDE);
        char* dst = ldsbuf + s * SLOTB;
        GLOAD_LDS16(src + lane * 16, dst);                               // k,e  (1024B)
        if (lane < 32) GLOAD_LDS16(src + 1024 + lane * 16, dst + 1024);  // qe   (512B)
        if (lane < 2)  GLOAD_LDS16(src + 1536 + cg * 32 + lane * 16, dst + 1536); // v slice (32B)
        if (lane == 0) GLOAD_LDS16(src + 2048, dst + 1568);              // sc   (16B)
    }
}

// 256 blocks x 128 threads (2 waves). bh = blk&15 keeps a stream on one XCD.
// cg = blk>>4 (16 col-groups x 8 cols). 16 lanes/col, 8 rows/lane.
__global__ __launch_bounds__(128) void scan_kernel(
    const float* __restrict__ sb, float* __restrict__ ov)
{
    __shared__ char lds[2 * TOKB * SLOTB];   // 51200 B

    const int tid = threadIdx.x;
    const int blk = blockIdx.x;
    const int bh = blk & 15;
    const int cg = blk >> 4;
    const int b = bh >> 3, h = bh & 7;
    const int cl = tid >> 4;      // 0..7
    const int rg = tid & 15;
    const int col = cg * 8 + cl;
    const int w = tid >> 6;
    const int lane = tid & 63;

    float S0 = 0.f, S1 = 0.f, S2 = 0.f, S3 = 0.f, S4 = 0.f, S5 = 0.f, S6 = 0.f, S7 = 0.f;

    const size_t base = (size_t)b * 2048 * 8 + h;
    const float* p0 = sb + base * RECF;
    size_t oidx = base * 128 + col;

    stage_batch(p0, lds, 0, w, lane, cg);
    __syncthreads();

    int cur = 0;
    for (int t0 = 0; t0 < 2048; t0 += TOKB) {
        if (t0 + TOKB < 2048)
            stage_batch(p0, lds + (cur ^ 1) * (TOKB * SLOTB), t0 + TOKB, w, lane, cg);

        const char* bufp = lds + cur * (TOKB * SLOTB);
#pragma unroll
        for (int s = 0; s < TOKB; ++s) {
            const char* rec = bufp + s * SLOTB;
            const float4 ka = *(const float4*)(rec + rg * 32);
            const float4 kb = *(const float4*)(rec + rg * 32 + 16);
            const float4 ea = *(const float4*)(rec + 512 + rg * 32);
            const float4 eb = *(const float4*)(rec + 512 + rg * 32 + 16);
            const float4 qa = *(const float4*)(rec + 1024 + rg * 32);
            const float4 qb = *(const float4*)(rec + 1024 + rg * 32 + 16);
            const float  vc = *(const float*)(rec + 1536 + cl * 4);
            const float4 sc = *(const float4*)(rec + 1568);

            // m = k .* S  (reused for bS and keS)
            const float m0 = ka.x * S0, m1 = ka.y * S1, m2 = ka.z * S2, m3 = ka.w * S3;
            const float m4 = kb.x * S4, m5 = kb.y * S5, m6 = kb.z * S6, m7 = kb.w * S7;
            float bS  = ((m0 + m1) + (m2 + m3)) + ((m4 + m5) + (m6 + m7));
            float keS = ((ea.x * m0 + ea.y * m1) + (ea.z * m2 + ea.w * m3))
                      + ((eb.x * m4 + eb.y * m5) + (eb.z * m6 + eb.w * m7));
            float qeS = ((qa.x * S0 + qa.y * S1) + (qa.z * S2 + qa.w * S3))
                      + ((qb.x * S4 + qb.y * S5) + (qb.z * S6 + qb.w * S7));
            bS = red16(bS); keS = red16(keS); qeS = red16(qeS);

            const float bSb = sc.x * bS;
            const float ks  = keS - bSb * sc.y;
            const float wv  = vc - sc.x * ks;
            const float o   = (qeS - bSb * sc.z) + wv * sc.w;

            // S' = e .* (S - bSb*k) + wv*k
            S0 = ea.x * (S0 - bSb * ka.x) + wv * ka.x;
            S1 = ea.y * (S1 - bSb * ka.y) + wv * ka.y;
            S2 = ea.z * (S2 - bSb * ka.z) + wv * ka.z;
            S3 = ea.w * (S3 - bSb * ka.w) + wv * ka.w;
            S4 = eb.x * (S4 - bSb * kb.x) + wv * kb.x;
            S5 = eb.y * (S5 - bSb * kb.y) + wv * kb.y;
            S6 = eb.z * (S6 - bSb * kb.z) + wv * kb.z;
            S7 = eb.w * (S7 - bSb * kb.w) + wv * kb.w;

            if (rg == 0) ov[oidx + (size_t)s * 1024] = o;
        }
        __syncthreads();
        cur ^= 1;
        oidx += (size_t)TOKB * 1024;
    }
}

// ---------------- post: writes bf16 y
__global__ __launch_bounds__(128) void post_kernel(
    const float* __restrict__ ov, const float* __restrict__ f1og,
    const float* __restrict__ Wog2, const float* __restrict__ normw,
    u16* __restrict__ ybf)
{
    const int gid = blockIdx.x;
    const int h = gid & 7;
    const int row = gid >> 3;
    const int tid = threadIdx.x;
    const int col = h * 128 + tid;

    __shared__ float ogs[128];
    __shared__ float red[128];

    ogs[tid] = f1og[(size_t)row * 256 + 128 + tid];
    __syncthreads();

    float g = 0.f;
#pragma unroll 8
    for (int i = 0; i < 128; i++) g += ogs[i] * Wog2[(size_t)i * 1024 + col];

    const float o = ov[(size_t)row * 1024 + col];
    const float y = o * sigmf(g);

    red[tid] = y * y;
    __syncthreads();
    for (int off = 64; off > 0; off >>= 1) {
        if (tid < off) red[tid] += red[tid + off];
        __syncthreads();
    }
    const float rms = rsqrtf(red[0] * (1.f / 128.f) + 1e-6f);
    ybf[(size_t)row * 1024 + col] = f2bf(y * rms * normw[col]);
}

extern "C" void kernel_launch(void* const* d_in, const int* in_sizes, int n_in,
                              void* d_out, int out_size, void* d_ws, size_t ws_size,
                              hipStream_t stream)
{
    const float* x     = (const float*)d_in[0];
    const float* Wq    = (const float*)d_in[1];
    const float* Wk    = (const float*)d_in[2];
    const float* Wv    = (const float*)d_in[3];
    const float* Wf1   = (const float*)d_in[4];
    const float* Wf2   = (const float*)d_in[5];
    const float* Wbeta = (const float*)d_in[6];
    const float* Wog1  = (const float*)d_in[7];
    const float* Wog2  = (const float*)d_in[8];
    const float* normw = (const float*)d_in[9];
    const float* Wo    = (const float*)d_in[10];
    float* out = (float*)d_out;

    float* ws   = (float*)d_ws;
    float* qraw = ws;                                 // 4M floats
    float* kraw = ws + SZT;
    float* vraw = ws + 2 * SZT;
    float* sb   = ws + 3 * SZT;                       // 32768*520 = 17.04M floats
    float* ov   = sb + (size_t)32768 * RECF;          // 4M floats; W split bufs live here early
    float* f1og = ov + SZT;                           // 1M floats (4096*256)
    float* wcat = f1og + (size_t)4096 * 256;          // 0.26M floats
    float* xsp  = wcat + (size_t)1024 * 256;          // 4M floats (xh, xl as u16)
    float* wot  = xsp + SZT;                          // 0.5M floats (WoT)

    u16* xh  = (u16*)xsp;
    u16* xl  = xh + SZT;
    u16* WoT = (u16*)wot;

    u16* WqTh = (u16*)ov;                             // 6 x 1M u16 inside ov
    u16* WqTl = WqTh + (size_t)1024 * 1024;
    u16* WkTh = WqTl + (size_t)1024 * 1024;
    u16* WkTl = WkTh + (size_t)1024 * 1024;
    u16* WvTh = WkTl + (size_t)1024 * 1024;
    u16* WvTl = WvTh + (size_t)1024 * 1024;

    u16* ybf = (u16*)vraw;                            // vraw dead after prep

    dim3 b256(256), b128(128);

    wtrans_split<<<dim3(32, 32), b256, 0, stream>>>(Wq, WqTh, WqTl);
    wtrans_split<<<dim3(32, 32), b256, 0, stream>>>(Wk, WkTh, WkTl);
    wtrans_split<<<dim3(32, 32), b256, 0, stream>>>(Wv, WvTh, WvTl);
    wtrans<<<dim3(32, 32), b256, 0, stream>>>(Wo, WoT);
    conv_split<<<2048, b256, 0, stream>>>(x, xh, xl);
    wcat_kernel<<<1024, b256, 0, stream>>>(Wf1, Wog1, wcat);

    gemm_bf16_split<<<dim3(8, 32), b256, 0, stream>>>(xh, xl, WqTh, WqTl, qraw, 4096, 1024, 1024);
    gemm_bf16_split<<<dim3(8, 32), b256, 0, stream>>>(xh, xl, WkTh, WkTl, kraw, 4096, 1024, 1024);
    gemm_bf16_split<<<dim3(8, 32), b256, 0, stream>>>(xh, xl, WvTh, WvTl, vraw, 4096, 1024, 1024);
    gemm_f32<<<dim3(4, 64), b256, 0, stream>>>(x, wcat, f1og, 4096, 256, 1024);

    prep_kernel<<<32768, b128, 0, stream>>>(x, Wbeta, Wf2, f1og, qraw, kraw, vraw, sb);
    scan_kernel<<<256, b128, 0, stream>>>(sb, ov);
    post_kernel<<<32768, b128, 0, stream>>>(ov, f1og, Wog2, normw, ybf);

    gemm_bf16<<<dim3(8, 32), b256, 0, stream>>>(ybf, WoT, out, 4096, 1024, 1024);
}

// Round 10
// 926.305 us; speedup vs baseline: 1.2237x; 1.2237x over previous
//
#include <hip/hip_runtime.h>
#include <cmath>

// DenseRnn on MI355X. B=2, N=2048, D=1024, H=8, HD=128.
//
// Pipeline:
//  wtrans_split_g: Wq/Wk/Wv [1024x1024], Wcat [1024x256], Wf2/Wog2 [128x1024]
//    -> bf16 hi/lo transposed; wtrans: Wo -> plain bf16
//  conv_split: x -> bf16 hi/lo; wcat: [Wf1|Wog1]
//  gemm_bf16_split (3-term bf16x2 ~ fp32): qraw/kraw/vraw = x@W;
//    f1og = x@Wcat; fraw = f1@Wf2; gate = og1@Wog2 (K=128, lda=256)
//  beta_kernel: beta = 2*sigmoid(x@Wbeta)  [4096x8]
//  prep: silu/l2norm/e; PERMUTED record sb[520] = {k,e,qe (perm), v, sc}
//  scan: 16 lanes/col x 8 rows/lane, conflict-free b128 reads (perm layout),
//    pure-DPP reductions, explicit 2-deep LDS->reg pipeline (sched_barrier),
//    16-token double-buffered LDS ring via global_load_lds.
//  post: y = o*sigmoid(gate), per-head RMS, *norm_w -> bf16
//  gemm_bf16: y@Wo -> out

#define SZT ((size_t)4096 * 1024)
#define RECF 520
#define RECSTRIDE 4160     // 8*RECF floats between consecutive tokens of a stream
#define TOKB 16
#define SLOTB 1600         // k 512 | e 512 | qe 512 | v 32 | sc 16 | pad

typedef unsigned short u16;
typedef __attribute__((ext_vector_type(8))) short short8;
typedef __attribute__((ext_vector_type(4))) float f32x4;

__device__ __forceinline__ float sigmf(float x) { return 1.f / (1.f + expf(-x)); }
__device__ __forceinline__ float siluf(float x) { return x * sigmf(x); }
__device__ __forceinline__ u16 f2bf(float f) {
    unsigned int u = __float_as_uint(f);
    unsigned int r = (u + 0x7FFFu + ((u >> 16) & 1u)) >> 16;
    return (u16)r;
}
__device__ __forceinline__ float bf2f(u16 h) { return __uint_as_float((unsigned int)h << 16); }
__device__ __forceinline__ void splitbf(float f, u16& hi, u16& lo) {
    hi = f2bf(f);
    lo = f2bf(f - bf2f(hi));
}

#define GLOAD_LDS16(gp, lp) __builtin_amdgcn_global_load_lds( \
    (const __attribute__((address_space(1))) void*)(gp),      \
    (__attribute__((address_space(3))) void*)(lp), 16, 0, 0)

// ---------------- generic transpose+split: W [K][N] -> WTh/WTl [N][K]
__global__ __launch_bounds__(256) void wtrans_split_g(
    const float* __restrict__ W, u16* __restrict__ WTh, u16* __restrict__ WTl,
    int K, int N)
{
    __shared__ float t[32][33];
    const int tx = threadIdx.x & 31, ty = threadIdx.x >> 5;
    const int n0 = blockIdx.x * 32, k0 = blockIdx.y * 32;
#pragma unroll
    for (int i = 0; i < 4; i++)
        t[ty + i * 8][tx] = W[(size_t)(k0 + ty + i * 8) * N + n0 + tx];
    __syncthreads();
#pragma unroll
    for (int i = 0; i < 4; i++) {
        u16 hi, lo;
        splitbf(t[tx][ty + i * 8], hi, lo);
        WTh[(size_t)(n0 + ty + i * 8) * K + k0 + tx] = hi;
        WTl[(size_t)(n0 + ty + i * 8) * K + k0 + tx] = lo;
    }
}

// ---------------- plain transpose (Wo)
__global__ __launch_bounds__(256) void wtrans(const float* __restrict__ W, u16* __restrict__ WT)
{
    __shared__ float t[32][33];
    const int tx = threadIdx.x & 31, ty = threadIdx.x >> 5;
    const int n0 = blockIdx.x * 32, k0 = blockIdx.y * 32;
#pragma unroll
    for (int i = 0; i < 4; i++)
        t[ty + i * 8][tx] = W[(size_t)(k0 + ty + i * 8) * 1024 + n0 + tx];
    __syncthreads();
#pragma unroll
    for (int i = 0; i < 4; i++)
        WT[(size_t)(n0 + ty + i * 8) * 1024 + k0 + tx] = f2bf(t[tx][ty + i * 8]);
}

// ---------------- fp32 -> bf16 hi/lo elementwise (size = grid*256*8)
__global__ __launch_bounds__(256) void conv_split(
    const float* __restrict__ in, u16* __restrict__ oh, u16* __restrict__ ol)
{
    const size_t i = ((size_t)blockIdx.x * 256 + threadIdx.x) * 8;
    short8 rh, rl;
#pragma unroll
    for (int j = 0; j < 8; j++) {
        u16 hi, lo;
        splitbf(in[i + j], hi, lo);
        rh[j] = (short)hi; rl[j] = (short)lo;
    }
    *(short8*)&oh[i] = rh;
    *(short8*)&ol[i] = rl;
}

// ---------------- concat Wf1|Wog1 -> Wcat [1024][256]
__global__ __launch_bounds__(256) void wcat_kernel(
    const float* __restrict__ Wf1, const float* __restrict__ Wog1, float* __restrict__ Wcat)
{
    const int idx = blockIdx.x * 256 + threadIdx.x;
    const int k = idx >> 8, j = idx & 255;
    Wcat[idx] = (j < 128) ? Wf1[k * 128 + j] : Wog1[k * 128 + j - 128];
}

// ---------------- beta = 2*sigmoid(x @ Wbeta) ; one block per row
__global__ __launch_bounds__(256) void beta_kernel(
    const float* __restrict__ x, const float* __restrict__ Wbeta, float* __restrict__ beta)
{
    const int row = blockIdx.x;
    const int tid = threadIdx.x;
    const int lane = tid & 63, wid = tid >> 6;
    __shared__ float wsum[4][8];
    float4 xv = *(const float4*)&x[(size_t)row * 1024 + tid * 4];
    float p[8];
#pragma unroll
    for (int h = 0; h < 8; h++)
        p[h] = xv.x * Wbeta[(size_t)(tid * 4 + 0) * 8 + h]
             + xv.y * Wbeta[(size_t)(tid * 4 + 1) * 8 + h]
             + xv.z * Wbeta[(size_t)(tid * 4 + 2) * 8 + h]
             + xv.w * Wbeta[(size_t)(tid * 4 + 3) * 8 + h];
#pragma unroll
    for (int off = 32; off >= 1; off >>= 1)
#pragma unroll
        for (int h = 0; h < 8; h++) p[h] += __shfl_xor(p[h], off);
    if (lane == 0)
#pragma unroll
        for (int h = 0; h < 8; h++) wsum[wid][h] = p[h];
    __syncthreads();
    if (tid < 8) {
        float s = wsum[0][tid] + wsum[1][tid] + wsum[2][tid] + wsum[3][tid];
        beta[(size_t)row * 8 + tid] = 2.f * sigmf(s);
    }
}

// ---------------- split bf16 MFMA GEMM: C[M,N] = (Ah+Al)[lda rows] @ (BTh+BTl)[ldb]^T
__global__ __launch_bounds__(256) void gemm_bf16_split(
    const u16* __restrict__ Ah, const u16* __restrict__ Al,
    const u16* __restrict__ BTh, const u16* __restrict__ BTl,
    float* __restrict__ C, int M, int N, int K, int lda, int ldb)
{
    __shared__ u16 AsH[128 * 32];
    __shared__ u16 AsL[128 * 32];
    __shared__ u16 BsH[128 * 32];
    __shared__ u16 BsL[128 * 32];
    const int tid = threadIdx.x;
    const int lane = tid & 63;
    const int w = tid >> 6;
    const int wr = w >> 1, wc = w & 1;
    const int row0 = blockIdx.y * 128;
    const int col0 = blockIdx.x * 128;
    const int mrow = lane & 15;
    const int kgrp = (lane >> 4) * 8;

    f32x4 acc[4][4] = {};

    const int off0 = w * 1024 + lane * 16;
    const int r0 = off0 >> 6, kl0 = (off0 & 63) >> 1;
    const int off1 = off0 + 4096;
    const int r1 = off1 >> 6, kl1 = (off1 & 63) >> 1;

    for (int kt = 0; kt < K; kt += 32) {
        GLOAD_LDS16(Ah  + (size_t)(row0 + r0) * lda + kt + kl0, (char*)AsH + w * 1024);
        GLOAD_LDS16(Ah  + (size_t)(row0 + r1) * lda + kt + kl1, (char*)AsH + w * 1024 + 4096);
        GLOAD_LDS16(Al  + (size_t)(row0 + r0) * lda + kt + kl0, (char*)AsL + w * 1024);
        GLOAD_LDS16(Al  + (size_t)(row0 + r1) * lda + kt + kl1, (char*)AsL + w * 1024 + 4096);
        GLOAD_LDS16(BTh + (size_t)(col0 + r0) * ldb + kt + kl0, (char*)BsH + w * 1024);
        GLOAD_LDS16(BTh + (size_t)(col0 + r1) * ldb + kt + kl1, (char*)BsH + w * 1024 + 4096);
        GLOAD_LDS16(BTl + (size_t)(col0 + r0) * ldb + kt + kl0, (char*)BsL + w * 1024);
        GLOAD_LDS16(BTl + (size_t)(col0 + r1) * ldb + kt + kl1, (char*)BsL + w * 1024 + 4096);
        __syncthreads();

        short8 aH[4], aL[4], bH[4], bL[4];
#pragma unroll
        for (int mi = 0; mi < 4; ++mi) {
            aH[mi] = *(const short8*)&AsH[(wr * 64 + mi * 16 + mrow) * 32 + kgrp];
            aL[mi] = *(const short8*)&AsL[(wr * 64 + mi * 16 + mrow) * 32 + kgrp];
        }
#pragma unroll
        for (int ni = 0; ni < 4; ++ni) {
            bH[ni] = *(const short8*)&BsH[(wc * 64 + ni * 16 + mrow) * 32 + kgrp];
            bL[ni] = *(const short8*)&BsL[(wc * 64 + ni * 16 + mrow) * 32 + kgrp];
        }
#pragma unroll
        for (int mi = 0; mi < 4; ++mi)
#pragma unroll
            for (int ni = 0; ni < 4; ++ni) {
                acc[mi][ni] = __builtin_amdgcn_mfma_f32_16x16x32_bf16(aH[mi], bH[ni], acc[mi][ni], 0, 0, 0);
                acc[mi][ni] = __builtin_amdgcn_mfma_f32_16x16x32_bf16(aL[mi], bH[ni], acc[mi][ni], 0, 0, 0);
                acc[mi][ni] = __builtin_amdgcn_mfma_f32_16x16x32_bf16(aH[mi], bL[ni], acc[mi][ni], 0, 0, 0);
            }
        __syncthreads();
    }

    const int crow = (lane >> 4) * 4;
#pragma unroll
    for (int mi = 0; mi < 4; ++mi)
#pragma unroll
        for (int ni = 0; ni < 4; ++ni)
#pragma unroll
            for (int j = 0; j < 4; ++j)
                C[(size_t)(row0 + wr * 64 + mi * 16 + crow + j) * N + col0 + wc * 64 + ni * 16 + mrow]
                    = acc[mi][ni][j];
}

// ---------------- plain bf16 MFMA GEMM (final projection)
__global__ __launch_bounds__(256) void gemm_bf16(
    const u16* __restrict__ A, const u16* __restrict__ BT, float* __restrict__ C,
    int M, int N, int K)
{
    __shared__ u16 As[128 * 32];
    __shared__ u16 Bs[128 * 32];
    const int tid = threadIdx.x;
    const int lane = tid & 63;
    const int w = tid >> 6;
    const int wr = w >> 1, wc = w & 1;
    const int row0 = blockIdx.y * 128;
    const int col0 = blockIdx.x * 128;
    const int mrow = lane & 15;
    const int kgrp = (lane >> 4) * 8;

    f32x4 acc[4][4] = {};

    const int off0 = w * 1024 + lane * 16;
    const int r0 = off0 >> 6, kl0 = (off0 & 63) >> 1;
    const int off1 = off0 + 4096;
    const int r1 = off1 >> 6, kl1 = (off1 & 63) >> 1;

    for (int kt = 0; kt < K; kt += 32) {
        GLOAD_LDS16(A  + (size_t)(row0 + r0) * K + kt + kl0, (char*)As + w * 1024);
        GLOAD_LDS16(A  + (size_t)(row0 + r1) * K + kt + kl1, (char*)As + w * 1024 + 4096);
        GLOAD_LDS16(BT + (size_t)(col0 + r0) * K + kt + kl0, (char*)Bs + w * 1024);
        GLOAD_LDS16(BT + (size_t)(col0 + r1) * K + kt + kl1, (char*)Bs + w * 1024 + 4096);
        __syncthreads();

        short8 aF[4], bF[4];
#pragma unroll
        for (int mi = 0; mi < 4; ++mi)
            aF[mi] = *(const short8*)&As[(wr * 64 + mi * 16 + mrow) * 32 + kgrp];
#pragma unroll
        for (int ni = 0; ni < 4; ++ni)
            bF[ni] = *(const short8*)&Bs[(wc * 64 + ni * 16 + mrow) * 32 + kgrp];
#pragma unroll
        for (int mi = 0; mi < 4; ++mi)
#pragma unroll
            for (int ni = 0; ni < 4; ++ni)
                acc[mi][ni] = __builtin_amdgcn_mfma_f32_16x16x32_bf16(aF[mi], bF[ni], acc[mi][ni], 0, 0, 0);
        __syncthreads();
    }

    const int crow = (lane >> 4) * 4;
#pragma unroll
    for (int mi = 0; mi < 4; ++mi)
#pragma unroll
        for (int ni = 0; ni < 4; ++ni)
#pragma unroll
            for (int j = 0; j < 4; ++j)
                C[(size_t)(row0 + wr * 64 + mi * 16 + crow + j) * N + col0 + wc * 64 + ni * 16 + mrow]
                    = acc[mi][ni][j];
}

// ---------------- prep: block per (row,h), 128 thr. Writes PERMUTED record.
// perm(j) = ((j&4)<<4) + ((j>>3)<<2) + (j&3): lane rg later reads its 8 elems
// as float4 at byte rg*16 and 256+rg*16 -> conflict-free (16B lane stride).
__global__ __launch_bounds__(128) void prep_kernel(
    const float* __restrict__ qraw, const float* __restrict__ kraw,
    const float* __restrict__ vraw, const float* __restrict__ fraw,
    const float* __restrict__ beta, float* __restrict__ sb)
{
    const int gid = blockIdx.x;
    const int h = gid & 7;
    const int row = gid >> 3;
    const int tid = threadIdx.x;
    const int col = h * 128 + tid;
    const size_t rbase = (size_t)row * 1024;

    __shared__ float red[3][128];

    const float ksil = siluf(kraw[rbase + col]);
    red[0][tid] = ksil * ksil;
    __syncthreads();
    for (int off = 64; off > 0; off >>= 1) {
        if (tid < off) red[0][tid] += red[0][tid + off];
        __syncthreads();
    }
    const float rn = rsqrtf(red[0][0] + 1e-6f);
    __syncthreads();

    const float kn = ksil * rn;
    const float e  = sigmf(fraw[rbase + col]);
    const float qs = siluf(qraw[rbase + col]);
    const float vs = siluf(vraw[rbase + col]);
    const float kev = e * kn;
    const float qev = e * qs;

    red[0][tid] = kev * kn;   // c
    red[1][tid] = qs * kev;   // d1
    red[2][tid] = qs * kn;    // d2
    __syncthreads();
    for (int off = 64; off > 0; off >>= 1) {
        if (tid < off) {
            red[0][tid] += red[0][tid + off];
            red[1][tid] += red[1][tid + off];
            red[2][tid] += red[2][tid + off];
        }
        __syncthreads();
    }

    const int p = ((tid & 4) << 4) + ((tid >> 3) << 2) + (tid & 3);
    float* o = sb + (size_t)gid * RECF;
    o[p]        = kn;
    o[128 + p]  = e;
    o[256 + p]  = qev;
    o[384 + tid] = vs;
    if (tid == 0) {
        o[512] = beta[(size_t)row * 8 + h];
        o[513] = red[0][0];
        o[514] = red[1][0];
        o[515] = red[2][0];
    }
}

// ---------------- scan
__device__ __forceinline__ float red16(float x)
{
    x += __int_as_float(__builtin_amdgcn_mov_dpp(__float_as_int(x), 0xB1,  0xF, 0xF, true));
    x += __int_as_float(__builtin_amdgcn_mov_dpp(__float_as_int(x), 0x4E,  0xF, 0xF, true));
    x += __int_as_float(__builtin_amdgcn_mov_dpp(__float_as_int(x), 0x141, 0xF, 0xF, true));
    x += __int_as_float(__builtin_amdgcn_mov_dpp(__float_as_int(x), 0x140, 0xF, 0xF, true));
    return x;
}

struct TR { float4 ka, kb, ea, eb, qa, qb, sc; float vc; };

__device__ __forceinline__ void ldtok(const char* __restrict__ rec, int rg, int cl, TR& T)
{
    T.ka = *(const float4*)(rec + rg * 16);
    T.kb = *(const float4*)(rec + 256 + rg * 16);
    T.ea = *(const float4*)(rec + 512 + rg * 16);
    T.eb = *(const float4*)(rec + 768 + rg * 16);
    T.qa = *(const float4*)(rec + 1024 + rg * 16);
    T.qb = *(const float4*)(rec + 1280 + rg * 16);
    T.vc = *(const float*)(rec + 1536 + cl * 4);
    T.sc = *(const float4*)(rec + 1568);
}

#define STEP(T, SOFF)                                                              \
  {                                                                                \
    const float m0 = T.ka.x * S0, m1 = T.ka.y * S1, m2 = T.ka.z * S2, m3 = T.ka.w * S3; \
    const float m4 = T.kb.x * S4, m5 = T.kb.y * S5, m6 = T.kb.z * S6, m7 = T.kb.w * S7; \
    float bS  = ((m0 + m1) + (m2 + m3)) + ((m4 + m5) + (m6 + m7));                 \
    float keS = ((T.ea.x * m0 + T.ea.y * m1) + (T.ea.z * m2 + T.ea.w * m3))        \
              + ((T.eb.x * m4 + T.eb.y * m5) + (T.eb.z * m6 + T.eb.w * m7));       \
    float qeS = ((T.qa.x * S0 + T.qa.y * S1) + (T.qa.z * S2 + T.qa.w * S3))        \
              + ((T.qb.x * S4 + T.qb.y * S5) + (T.qb.z * S6 + T.qb.w * S7));       \
    bS = red16(bS); keS = red16(keS); qeS = red16(qeS);                            \
    const float bSb = T.sc.x * bS;                                                 \
    const float ks  = keS - bSb * T.sc.y;                                          \
    const float wv  = T.vc - T.sc.x * ks;                                          \
    const float o   = (qeS - bSb * T.sc.z) + wv * T.sc.w;                          \
    S0 = T.ea.x * (S0 - bSb * T.ka.x) + wv * T.ka.x;                               \
    S1 = T.ea.y * (S1 - bSb * T.ka.y) + wv * T.ka.y;                               \
    S2 = T.ea.z * (S2 - bSb * T.ka.z) + wv * T.ka.z;                               \
    S3 = T.ea.w * (S3 - bSb * T.ka.w) + wv * T.ka.w;                               \
    S4 = T.eb.x * (S4 - bSb * T.kb.x) + wv * T.kb.x;                               \
    S5 = T.eb.y * (S5 - bSb * T.kb.y) + wv * T.kb.y;                               \
    S6 = T.eb.z * (S6 - bSb * T.kb.z) + wv * T.kb.z;                               \
    S7 = T.eb.w * (S7 - bSb * T.kb.w) + wv * T.kb.w;                               \
    if (rg == 0) ov[oidx + (size_t)(SOFF) * 1024] = o;                             \
  }

#define SBAR __builtin_amdgcn_sched_barrier(0)

__device__ __forceinline__ void stage_batch(
    const float* __restrict__ p0, char* ldsbuf, int t0, int w, int lane, int cg)
{
    for (int s = w; s < TOKB; s += 2) {
        const char* src = (const char*)(p0 + (size_t)(t0 + s) * RECSTRIDE);
        char* dst = ldsbuf + s * SLOTB;
        GLOAD_LDS16(src + lane * 16, dst);                               // k,e (perm)
        if (lane < 32) GLOAD_LDS16(src + 1024 + lane * 16, dst + 1024);  // qe
        if (lane < 2)  GLOAD_LDS16(src + 1536 + cg * 32 + lane * 16, dst + 1536); // v slice
        if (lane == 0) GLOAD_LDS16(src + 2048, dst + 1568);              // sc
    }
}

// 256 blocks x 128 threads (2 waves). bh = blk&15 keeps stream on one XCD.
__global__ __launch_bounds__(128) void scan_kernel(
    const float* __restrict__ sb, float* __restrict__ ov)
{
    __shared__ char lds[2 * TOKB * SLOTB];   // 51200 B

    const int tid = threadIdx.x;
    const int blk = blockIdx.x;
    const int bh = blk & 15;
    const int cg = blk >> 4;
    const int b = bh >> 3, h = bh & 7;
    const int cl = tid >> 4;
    const int rg = tid & 15;
    const int col = cg * 8 + cl;
    const int w = tid >> 6;
    const int lane = tid & 63;

    float S0 = 0.f, S1 = 0.f, S2 = 0.f, S3 = 0.f, S4 = 0.f, S5 = 0.f, S6 = 0.f, S7 = 0.f;

    const size_t base = (size_t)b * 2048 * 8 + h;
    const float* p0 = sb + base * RECF;
    size_t oidx = base * 128 + col;

    stage_batch(p0, lds, 0, w, lane, cg);
    __syncthreads();

    int cur = 0;
    for (int t0 = 0; t0 < 2048; t0 += TOKB) {
        if (t0 + TOKB < 2048)
            stage_batch(p0, lds + (cur ^ 1) * (TOKB * SLOTB), t0 + TOKB, w, lane, cg);

        const char* bufp = lds + cur * (TOKB * SLOTB);
        TR A, B;
        ldtok(bufp, rg, cl, A); SBAR;
#pragma unroll
        for (int s = 0; s < TOKB; s += 2) {
            ldtok(bufp + (s + 1) * SLOTB, rg, cl, B); SBAR;
            STEP(A, s);
            if (s + 2 < TOKB) { ldtok(bufp + (s + 2) * SLOTB, rg, cl, A); SBAR; }
            STEP(B, s + 1);
        }
        __syncthreads();
        cur ^= 1;
        oidx += (size_t)TOKB * 1024;
    }
}

// ---------------- post: y = o*sigmoid(gate); per-head RMS; *norm_w -> bf16
__global__ __launch_bounds__(128) void post_kernel(
    const float* __restrict__ ov, const float* __restrict__ gate,
    const float* __restrict__ normw, u16* __restrict__ ybf)
{
    const int gid = blockIdx.x;
    const int h = gid & 7;
    const int row = gid >> 3;
    const int tid = threadIdx.x;
    const int col = h * 128 + tid;

    __shared__ float red[128];

    const float o = ov[(size_t)row * 1024 + col];
    const float y = o * sigmf(gate[(size_t)row * 1024 + col]);

    red[tid] = y * y;
    __syncthreads();
    for (int off = 64; off > 0; off >>= 1) {
        if (tid < off) red[tid] += red[tid + off];
        __syncthreads();
    }
    const float rms = rsqrtf(red[0] * (1.f / 128.f) + 1e-6f);
    ybf[(size_t)row * 1024 + col] = f2bf(y * rms * normw[col]);
}

extern "C" void kernel_launch(void* const* d_in, const int* in_sizes, int n_in,
                              void* d_out, int out_size, void* d_ws, size_t ws_size,
                              hipStream_t stream)
{
    const float* x     = (const float*)d_in[0];
    const float* Wq    = (const float*)d_in[1];
    const float* Wk    = (const float*)d_in[2];
    const float* Wv    = (const float*)d_in[3];
    const float* Wf1   = (const float*)d_in[4];
    const float* Wf2   = (const float*)d_in[5];
    const float* Wbeta = (const float*)d_in[6];
    const float* Wog1  = (const float*)d_in[7];
    const float* Wog2  = (const float*)d_in[8];
    const float* normw = (const float*)d_in[9];
    const float* Wo    = (const float*)d_in[10];
    float* out = (float*)d_out;

    float* ws   = (float*)d_ws;
    float* qraw = ws;                                  // 4M f
    float* kraw = qraw + SZT;                          // 4M f (gate after prep)
    float* vraw = kraw + SZT;                          // 4M f (ybf after prep)
    float* sb   = vraw + SZT;                          // 17.04M f (early: xh/xl, wcat, f1og)
    float* ov   = sb + (size_t)32768 * RECF;           // 4M f (early: W splits; then fraw; then scan)
    float* wot  = ov + SZT;                            // 0.5M f
    float* wcatT= wot + 524288;                        // 0.25M f
    float* wfog = wcatT + 262144;                      // 0.25M f
    float* f1sp = wfog + 262144;                       // 1M f
    float* betap= f1sp + 1048576;                      // 32K f

    // overlapped (pre-prep) buffers inside sb
    u16*   xh   = (u16*)sb;                            // 4M u16
    u16*   xl   = xh + SZT;                            // 4M u16
    float* wcat = sb + SZT;                            // 0.26M f
    float* f1og = wcat + 262144;                       // 1M f

    // weight splits inside ov (dead before fraw written)
    u16* WqTh = (u16*)ov;
    u16* WqTl = WqTh + (size_t)1024 * 1024;
    u16* WkTh = WqTl + (size_t)1024 * 1024;
    u16* WkTl = WkTh + (size_t)1024 * 1024;
    u16* WvTh = WkTl + (size_t)1024 * 1024;
    u16* WvTl = WvTh + (size_t)1024 * 1024;
    float* fraw = ov;                                  // after q/k/v gemms

    u16* WoT    = (u16*)wot;
    u16* WcatTh = (u16*)wcatT;
    u16* WcatTl = WcatTh + (size_t)256 * 1024;
    u16* Wf2Th  = (u16*)wfog;
    u16* Wf2Tl  = Wf2Th + (size_t)1024 * 128;
    u16* Wog2Th = Wf2Tl + (size_t)1024 * 128;
    u16* Wog2Tl = Wog2Th + (size_t)1024 * 128;
    u16* f1ogh  = (u16*)f1sp;
    u16* f1ogl  = f1ogh + (size_t)4096 * 256;

    float* gate = kraw;
    u16*   ybf  = (u16*)vraw;

    dim3 b256(256), b128(128);

    wtrans_split_g<<<dim3(32, 32), b256, 0, stream>>>(Wq, WqTh, WqTl, 1024, 1024);
    wtrans_split_g<<<dim3(32, 32), b256, 0, stream>>>(Wk, WkTh, WkTl, 1024, 1024);
    wtrans_split_g<<<dim3(32, 32), b256, 0, stream>>>(Wv, WvTh, WvTl, 1024, 1024);
    wtrans<<<dim3(32, 32), b256, 0, stream>>>(Wo, WoT);
    conv_split<<<2048, b256, 0, stream>>>(x, xh, xl);
    wcat_kernel<<<1024, b256, 0, stream>>>(Wf1, Wog1, wcat);
    wtrans_split_g<<<dim3(8, 32), b256, 0, stream>>>(wcat, WcatTh, WcatTl, 1024, 256);
    wtrans_split_g<<<dim3(32, 4), b256, 0, stream>>>(Wf2, Wf2Th, Wf2Tl, 128, 1024);
    wtrans_split_g<<<dim3(32, 4), b256, 0, stream>>>(Wog2, Wog2Th, Wog2Tl, 128, 1024);
    beta_kernel<<<4096, b256, 0, stream>>>(x, Wbeta, betap);

    gemm_bf16_split<<<dim3(8, 32), b256, 0, stream>>>(xh, xl, WqTh, WqTl, qraw, 4096, 1024, 1024, 1024, 1024);
    gemm_bf16_split<<<dim3(8, 32), b256, 0, stream>>>(xh, xl, WkTh, WkTl, kraw, 4096, 1024, 1024, 1024, 1024);
    gemm_bf16_split<<<dim3(8, 32), b256, 0, stream>>>(xh, xl, WvTh, WvTl, vraw, 4096, 1024, 1024, 1024, 1024);
    gemm_bf16_split<<<dim3(2, 32), b256, 0, stream>>>(xh, xl, WcatTh, WcatTl, f1og, 4096, 256, 1024, 1024, 1024);
    conv_split<<<512, b256, 0, stream>>>(f1og, f1ogh, f1ogl);
    gemm_bf16_split<<<dim3(8, 32), b256, 0, stream>>>(f1ogh, f1ogl, Wf2Th, Wf2Tl, fraw, 4096, 1024, 128, 256, 128);

    prep_kernel<<<32768, b128, 0, stream>>>(qraw, kraw, vraw, fraw, betap, sb);
    gemm_bf16_split<<<dim3(8, 32), b256, 0, stream>>>(f1ogh + 128, f1ogl + 128, Wog2Th, Wog2Tl, gate, 4096, 1024, 128, 256, 128);
    scan_kernel<<<256, b128, 0, stream>>>(sb, ov);
    post_kernel<<<32768, b128, 0, stream>>>(ov, gate, normw, ybf);

    gemm_bf16<<<dim3(8, 32), b256, 0, stream>>>(ybf, WoT, out, 4096, 1024, 1024);
}

// Round 11
// 840.110 us; speedup vs baseline: 1.3492x; 1.1026x over previous
//
#include <hip/hip_runtime.h>
#include <cmath>

// DenseRnn on MI355X. B=2, N=2048, D=1024, H=8, HD=128.
//
//  wtrans_split_g: Wq/Wk/Wv, Wcat, Wf2/Wog2 -> bf16 hi/lo transposed; Wo plain
//  conv_split: x -> bf16 hi/lo; wcat: [Wf1|Wog1]
//  gemm_bf16_split (3-term bf16x2 ~ fp32): qraw/kraw/vraw = x@W;
//    f1og = x@Wcat; fraw = f1@Wf2; gate = og1@Wog2
//  beta_kernel: beta = 2*sigmoid(x@Wbeta)
//  prep: silu/l2norm/e; record sb[520] = {k,e,qe,v, sc@512} (plain layout)
//  scan: 32 lanes/col x 4 rows/lane -> 1024 waves = 1 wave/SIMD chip-wide
//    (R10 post-mortem: 16-lane geometry left half the SIMDs idle).
//    4-DPP + 1-swizzle reductions, contiguous float4 LDS reads (no perm
//    needed, conflict-free), 2-deep LDS->reg pipeline, 16-token dbuf ring.
//  post: y = o*sigmoid(gate), per-head RMS, *norm_w -> bf16
//  gemm_bf16: y@Wo -> out

#define SZT ((size_t)4096 * 1024)
#define RECF 520
#define RECSTRIDE 4160     // 8*RECF floats between consecutive tokens of a stream
#define TOKB 16
#define SLOTB 1600         // k 512 | e 512 | qe 512 | v 32 | sc 16 | pad

typedef unsigned short u16;
typedef __attribute__((ext_vector_type(8))) short short8;
typedef __attribute__((ext_vector_type(4))) float f32x4;

__device__ __forceinline__ float sigmf(float x) { return 1.f / (1.f + expf(-x)); }
__device__ __forceinline__ float siluf(float x) { return x * sigmf(x); }
__device__ __forceinline__ u16 f2bf(float f) {
    unsigned int u = __float_as_uint(f);
    unsigned int r = (u + 0x7FFFu + ((u >> 16) & 1u)) >> 16;
    return (u16)r;
}
__device__ __forceinline__ float bf2f(u16 h) { return __uint_as_float((unsigned int)h << 16); }
__device__ __forceinline__ void splitbf(float f, u16& hi, u16& lo) {
    hi = f2bf(f);
    lo = f2bf(f - bf2f(hi));
}

#define GLOAD_LDS16(gp, lp) __builtin_amdgcn_global_load_lds( \
    (const __attribute__((address_space(1))) void*)(gp),      \
    (__attribute__((address_space(3))) void*)(lp), 16, 0, 0)

// ---------------- generic transpose+split: W [K][N] -> WTh/WTl [N][K]
__global__ __launch_bounds__(256) void wtrans_split_g(
    const float* __restrict__ W, u16* __restrict__ WTh, u16* __restrict__ WTl,
    int K, int N)
{
    __shared__ float t[32][33];
    const int tx = threadIdx.x & 31, ty = threadIdx.x >> 5;
    const int n0 = blockIdx.x * 32, k0 = blockIdx.y * 32;
#pragma unroll
    for (int i = 0; i < 4; i++)
        t[ty + i * 8][tx] = W[(size_t)(k0 + ty + i * 8) * N + n0 + tx];
    __syncthreads();
#pragma unroll
    for (int i = 0; i < 4; i++) {
        u16 hi, lo;
        splitbf(t[tx][ty + i * 8], hi, lo);
        WTh[(size_t)(n0 + ty + i * 8) * K + k0 + tx] = hi;
        WTl[(size_t)(n0 + ty + i * 8) * K + k0 + tx] = lo;
    }
}

// ---------------- plain transpose (Wo)
__global__ __launch_bounds__(256) void wtrans(const float* __restrict__ W, u16* __restrict__ WT)
{
    __shared__ float t[32][33];
    const int tx = threadIdx.x & 31, ty = threadIdx.x >> 5;
    const int n0 = blockIdx.x * 32, k0 = blockIdx.y * 32;
#pragma unroll
    for (int i = 0; i < 4; i++)
        t[ty + i * 8][tx] = W[(size_t)(k0 + ty + i * 8) * 1024 + n0 + tx];
    __syncthreads();
#pragma unroll
    for (int i = 0; i < 4; i++)
        WT[(size_t)(n0 + ty + i * 8) * 1024 + k0 + tx] = f2bf(t[tx][ty + i * 8]);
}

// ---------------- fp32 -> bf16 hi/lo elementwise (size = grid*256*8)
__global__ __launch_bounds__(256) void conv_split(
    const float* __restrict__ in, u16* __restrict__ oh, u16* __restrict__ ol)
{
    const size_t i = ((size_t)blockIdx.x * 256 + threadIdx.x) * 8;
    short8 rh, rl;
#pragma unroll
    for (int j = 0; j < 8; j++) {
        u16 hi, lo;
        splitbf(in[i + j], hi, lo);
        rh[j] = (short)hi; rl[j] = (short)lo;
    }
    *(short8*)&oh[i] = rh;
    *(short8*)&ol[i] = rl;
}

// ---------------- concat Wf1|Wog1 -> Wcat [1024][256]
__global__ __launch_bounds__(256) void wcat_kernel(
    const float* __restrict__ Wf1, const float* __restrict__ Wog1, float* __restrict__ Wcat)
{
    const int idx = blockIdx.x * 256 + threadIdx.x;
    const int k = idx >> 8, j = idx & 255;
    Wcat[idx] = (j < 128) ? Wf1[k * 128 + j] : Wog1[k * 128 + j - 128];
}

// ---------------- beta = 2*sigmoid(x @ Wbeta) ; one block per row
__global__ __launch_bounds__(256) void beta_kernel(
    const float* __restrict__ x, const float* __restrict__ Wbeta, float* __restrict__ beta)
{
    const int row = blockIdx.x;
    const int tid = threadIdx.x;
    const int lane = tid & 63, wid = tid >> 6;
    __shared__ float wsum[4][8];
    float4 xv = *(const float4*)&x[(size_t)row * 1024 + tid * 4];
    float p[8];
#pragma unroll
    for (int h = 0; h < 8; h++)
        p[h] = xv.x * Wbeta[(size_t)(tid * 4 + 0) * 8 + h]
             + xv.y * Wbeta[(size_t)(tid * 4 + 1) * 8 + h]
             + xv.z * Wbeta[(size_t)(tid * 4 + 2) * 8 + h]
             + xv.w * Wbeta[(size_t)(tid * 4 + 3) * 8 + h];
#pragma unroll
    for (int off = 32; off >= 1; off >>= 1)
#pragma unroll
        for (int h = 0; h < 8; h++) p[h] += __shfl_xor(p[h], off);
    if (lane == 0)
#pragma unroll
        for (int h = 0; h < 8; h++) wsum[wid][h] = p[h];
    __syncthreads();
    if (tid < 8) {
        float s = wsum[0][tid] + wsum[1][tid] + wsum[2][tid] + wsum[3][tid];
        beta[(size_t)row * 8 + tid] = 2.f * sigmf(s);
    }
}

// ---------------- split bf16 MFMA GEMM: C[M,N] = (Ah+Al)[lda rows] @ (BTh+BTl)[ldb]^T
__global__ __launch_bounds__(256) void gemm_bf16_split(
    const u16* __restrict__ Ah, const u16* __restrict__ Al,
    const u16* __restrict__ BTh, const u16* __restrict__ BTl,
    float* __restrict__ C, int M, int N, int K, int lda, int ldb)
{
    __shared__ u16 AsH[128 * 32];
    __shared__ u16 AsL[128 * 32];
    __shared__ u16 BsH[128 * 32];
    __shared__ u16 BsL[128 * 32];
    const int tid = threadIdx.x;
    const int lane = tid & 63;
    const int w = tid >> 6;
    const int wr = w >> 1, wc = w & 1;
    const int row0 = blockIdx.y * 128;
    const int col0 = blockIdx.x * 128;
    const int mrow = lane & 15;
    const int kgrp = (lane >> 4) * 8;

    f32x4 acc[4][4] = {};

    const int off0 = w * 1024 + lane * 16;
    const int r0 = off0 >> 6, kl0 = (off0 & 63) >> 1;
    const int off1 = off0 + 4096;
    const int r1 = off1 >> 6, kl1 = (off1 & 63) >> 1;

    for (int kt = 0; kt < K; kt += 32) {
        GLOAD_LDS16(Ah  + (size_t)(row0 + r0) * lda + kt + kl0, (char*)AsH + w * 1024);
        GLOAD_LDS16(Ah  + (size_t)(row0 + r1) * lda + kt + kl1, (char*)AsH + w * 1024 + 4096);
        GLOAD_LDS16(Al  + (size_t)(row0 + r0) * lda + kt + kl0, (char*)AsL + w * 1024);
        GLOAD_LDS16(Al  + (size_t)(row0 + r1) * lda + kt + kl1, (char*)AsL + w * 1024 + 4096);
        GLOAD_LDS16(BTh + (size_t)(col0 + r0) * ldb + kt + kl0, (char*)BsH + w * 1024);
        GLOAD_LDS16(BTh + (size_t)(col0 + r1) * ldb + kt + kl1, (char*)BsH + w * 1024 + 4096);
        GLOAD_LDS16(BTl + (size_t)(col0 + r0) * ldb + kt + kl0, (char*)BsL + w * 1024);
        GLOAD_LDS16(BTl + (size_t)(col0 + r1) * ldb + kt + kl1, (char*)BsL + w * 1024 + 4096);
        __syncthreads();

        short8 aH[4], aL[4], bH[4], bL[4];
#pragma unroll
        for (int mi = 0; mi < 4; ++mi) {
            aH[mi] = *(const short8*)&AsH[(wr * 64 + mi * 16 + mrow) * 32 + kgrp];
            aL[mi] = *(const short8*)&AsL[(wr * 64 + mi * 16 + mrow) * 32 + kgrp];
        }
#pragma unroll
        for (int ni = 0; ni < 4; ++ni) {
            bH[ni] = *(const short8*)&BsH[(wc * 64 + ni * 16 + mrow) * 32 + kgrp];
            bL[ni] = *(const short8*)&BsL[(wc * 64 + ni * 16 + mrow) * 32 + kgrp];
        }
#pragma unroll
        for (int mi = 0; mi < 4; ++mi)
#pragma unroll
            for (int ni = 0; ni < 4; ++ni) {
                acc[mi][ni] = __builtin_amdgcn_mfma_f32_16x16x32_bf16(aH[mi], bH[ni], acc[mi][ni], 0, 0, 0);
                acc[mi][ni] = __builtin_amdgcn_mfma_f32_16x16x32_bf16(aL[mi], bH[ni], acc[mi][ni], 0, 0, 0);
                acc[mi][ni] = __builtin_amdgcn_mfma_f32_16x16x32_bf16(aH[mi], bL[ni], acc[mi][ni], 0, 0, 0);
            }
        __syncthreads();
    }

    const int crow = (lane >> 4) * 4;
#pragma unroll
    for (int mi = 0; mi < 4; ++mi)
#pragma unroll
        for (int ni = 0; ni < 4; ++ni)
#pragma unroll
            for (int j = 0; j < 4; ++j)
                C[(size_t)(row0 + wr * 64 + mi * 16 + crow + j) * N + col0 + wc * 64 + ni * 16 + mrow]
                    = acc[mi][ni][j];
}

// ---------------- plain bf16 MFMA GEMM (final projection)
__global__ __launch_bounds__(256) void gemm_bf16(
    const u16* __restrict__ A, const u16* __restrict__ BT, float* __restrict__ C,
    int M, int N, int K)
{
    __shared__ u16 As[128 * 32];
    __shared__ u16 Bs[128 * 32];
    const int tid = threadIdx.x;
    const int lane = tid & 63;
    const int w = tid >> 6;
    const int wr = w >> 1, wc = w & 1;
    const int row0 = blockIdx.y * 128;
    const int col0 = blockIdx.x * 128;
    const int mrow = lane & 15;
    const int kgrp = (lane >> 4) * 8;

    f32x4 acc[4][4] = {};

    const int off0 = w * 1024 + lane * 16;
    const int r0 = off0 >> 6, kl0 = (off0 & 63) >> 1;
    const int off1 = off0 + 4096;
    const int r1 = off1 >> 6, kl1 = (off1 & 63) >> 1;

    for (int kt = 0; kt < K; kt += 32) {
        GLOAD_LDS16(A  + (size_t)(row0 + r0) * K + kt + kl0, (char*)As + w * 1024);
        GLOAD_LDS16(A  + (size_t)(row0 + r1) * K + kt + kl1, (char*)As + w * 1024 + 4096);
        GLOAD_LDS16(BT + (size_t)(col0 + r0) * K + kt + kl0, (char*)Bs + w * 1024);
        GLOAD_LDS16(BT + (size_t)(col0 + r1) * K + kt + kl1, (char*)Bs + w * 1024 + 4096);
        __syncthreads();

        short8 aF[4], bF[4];
#pragma unroll
        for (int mi = 0; mi < 4; ++mi)
            aF[mi] = *(const short8*)&As[(wr * 64 + mi * 16 + mrow) * 32 + kgrp];
#pragma unroll
        for (int ni = 0; ni < 4; ++ni)
            bF[ni] = *(const short8*)&Bs[(wc * 64 + ni * 16 + mrow) * 32 + kgrp];
#pragma unroll
        for (int mi = 0; mi < 4; ++mi)
#pragma unroll
            for (int ni = 0; ni < 4; ++ni)
                acc[mi][ni] = __builtin_amdgcn_mfma_f32_16x16x32_bf16(aF[mi], bF[ni], acc[mi][ni], 0, 0, 0);
        __syncthreads();
    }

    const int crow = (lane >> 4) * 4;
#pragma unroll
    for (int mi = 0; mi < 4; ++mi)
#pragma unroll
        for (int ni = 0; ni < 4; ++ni)
#pragma unroll
            for (int j = 0; j < 4; ++j)
                C[(size_t)(row0 + wr * 64 + mi * 16 + crow + j) * N + col0 + wc * 64 + ni * 16 + mrow]
                    = acc[mi][ni][j];
}

// ---------------- prep: block per (row,h), 128 thr. Plain record layout.
__global__ __launch_bounds__(128) void prep_kernel(
    const float* __restrict__ qraw, const float* __restrict__ kraw,
    const float* __restrict__ vraw, const float* __restrict__ fraw,
    const float* __restrict__ beta, float* __restrict__ sb)
{
    const int gid = blockIdx.x;
    const int h = gid & 7;
    const int row = gid >> 3;
    const int tid = threadIdx.x;
    const int col = h * 128 + tid;
    const size_t rbase = (size_t)row * 1024;

    __shared__ float red[3][128];

    const float ksil = siluf(kraw[rbase + col]);
    red[0][tid] = ksil * ksil;
    __syncthreads();
    for (int off = 64; off > 0; off >>= 1) {
        if (tid < off) red[0][tid] += red[0][tid + off];
        __syncthreads();
    }
    const float rn = rsqrtf(red[0][0] + 1e-6f);
    __syncthreads();

    const float kn = ksil * rn;
    const float e  = sigmf(fraw[rbase + col]);
    const float qs = siluf(qraw[rbase + col]);
    const float vs = siluf(vraw[rbase + col]);
    const float kev = e * kn;
    const float qev = e * qs;

    red[0][tid] = kev * kn;   // c
    red[1][tid] = qs * kev;   // d1
    red[2][tid] = qs * kn;    // d2
    __syncthreads();
    for (int off = 64; off > 0; off >>= 1) {
        if (tid < off) {
            red[0][tid] += red[0][tid + off];
            red[1][tid] += red[1][tid + off];
            red[2][tid] += red[2][tid + off];
        }
        __syncthreads();
    }

    float* o = sb + (size_t)gid * RECF;
    o[tid]        = kn;
    o[128 + tid]  = e;
    o[256 + tid]  = qev;
    o[384 + tid]  = vs;
    if (tid == 0) {
        o[512] = beta[(size_t)row * 8 + h];
        o[513] = red[0][0];
        o[514] = red[1][0];
        o[515] = red[2][0];
    }
}

// ---------------- scan
// 32-lane sum: 4 DPP stages (within 16) + ds_swizzle xor16 (within 32-groups).
__device__ __forceinline__ float red32(float x)
{
    x += __int_as_float(__builtin_amdgcn_mov_dpp(__float_as_int(x), 0xB1,  0xF, 0xF, true));
    x += __int_as_float(__builtin_amdgcn_mov_dpp(__float_as_int(x), 0x4E,  0xF, 0xF, true));
    x += __int_as_float(__builtin_amdgcn_mov_dpp(__float_as_int(x), 0x141, 0xF, 0xF, true));
    x += __int_as_float(__builtin_amdgcn_mov_dpp(__float_as_int(x), 0x140, 0xF, 0xF, true));
    x += __int_as_float(__builtin_amdgcn_ds_swizzle(__float_as_int(x), 0x401F));
    return x;
}

struct TR { float4 k, e, q, sc; float vc; };

__device__ __forceinline__ void ldtok(const char* __restrict__ rec, int rg, int cl, TR& T)
{
    T.k  = *(const float4*)(rec + rg * 16);
    T.e  = *(const float4*)(rec + 512 + rg * 16);
    T.q  = *(const float4*)(rec + 1024 + rg * 16);
    T.vc = *(const float*)(rec + 1536 + cl * 4);
    T.sc = *(const float4*)(rec + 1568);
}

#define STEP(T, SOFF)                                                              \
  {                                                                                \
    const float m0 = T.k.x * S0, m1 = T.k.y * S1, m2 = T.k.z * S2, m3 = T.k.w * S3; \
    float bS  = (m0 + m1) + (m2 + m3);                                             \
    float keS = (T.e.x * m0 + T.e.y * m1) + (T.e.z * m2 + T.e.w * m3);             \
    float qeS = (T.q.x * S0 + T.q.y * S1) + (T.q.z * S2 + T.q.w * S3);             \
    bS = red32(bS); keS = red32(keS); qeS = red32(qeS);                            \
    const float bSb = T.sc.x * bS;                                                 \
    const float ks  = keS - bSb * T.sc.y;                                          \
    const float wv  = T.vc - T.sc.x * ks;                                          \
    const float o   = (qeS - bSb * T.sc.z) + wv * T.sc.w;                          \
    S0 = T.e.x * (S0 - bSb * T.k.x) + wv * T.k.x;                                  \
    S1 = T.e.y * (S1 - bSb * T.k.y) + wv * T.k.y;                                  \
    S2 = T.e.z * (S2 - bSb * T.k.z) + wv * T.k.z;                                  \
    S3 = T.e.w * (S3 - bSb * T.k.w) + wv * T.k.w;                                  \
    if (rg == 0) ov[oidx + (size_t)(SOFF) * 1024] = o;                             \
  }

#define SBAR __builtin_amdgcn_sched_barrier(0)

__device__ __forceinline__ void stage_batch(
    const float* __restrict__ p0, char* ldsbuf, int t0, int w, int lane, int cg)
{
    for (int s = w; s < TOKB; s += 4) {
        const char* src = (const char*)(p0 + (size_t)(t0 + s) * RECSTRIDE);
        char* dst = ldsbuf + s * SLOTB;
        GLOAD_LDS16(src + lane * 16, dst);                               // k,e (1024B)
        if (lane < 32) GLOAD_LDS16(src + 1024 + lane * 16, dst + 1024);  // qe (512B)
        if (lane < 2)  GLOAD_LDS16(src + 1536 + cg * 32 + lane * 16, dst + 1536); // v slice
        if (lane == 0) GLOAD_LDS16(src + 2048, dst + 1568);              // sc
    }
}

// 256 blocks x 256 threads (4 waves = 1024 waves total -> 1 wave/SIMD).
// bh = blk&15 keeps a stream's 16 blocks on one XCD. cg = blk>>4, 8 cols each;
// 32 lanes/col (lanes 0-31 / 32-63 of a wave are two adjacent cols), 4 rows/lane.
__global__ __launch_bounds__(256) void scan_kernel(
    const float* __restrict__ sb, float* __restrict__ ov)
{
    __shared__ char lds[2 * TOKB * SLOTB];   // 51200 B

    const int tid = threadIdx.x;
    const int blk = blockIdx.x;
    const int bh = blk & 15;
    const int cg = blk >> 4;
    const int b = bh >> 3, h = bh & 7;
    const int cl = tid >> 5;      // 0..7
    const int rg = tid & 31;
    const int col = cg * 8 + cl;
    const int w = tid >> 6;
    const int lane = tid & 63;

    float S0 = 0.f, S1 = 0.f, S2 = 0.f, S3 = 0.f;

    const size_t base = (size_t)b * 2048 * 8 + h;
    const float* p0 = sb + base * RECF;
    size_t oidx = base * 128 + col;

    stage_batch(p0, lds, 0, w, lane, cg);
    __syncthreads();

    int cur = 0;
    for (int t0 = 0; t0 < 2048; t0 += TOKB) {
        if (t0 + TOKB < 2048)
            stage_batch(p0, lds + (cur ^ 1) * (TOKB * SLOTB), t0 + TOKB, w, lane, cg);

        const char* bufp = lds + cur * (TOKB * SLOTB);
        TR A, B;
        ldtok(bufp, rg, cl, A); SBAR;
#pragma unroll
        for (int s = 0; s < TOKB; s += 2) {
            ldtok(bufp + (s + 1) * SLOTB, rg, cl, B); SBAR;
            STEP(A, s);
            if (s + 2 < TOKB) { ldtok(bufp + (s + 2) * SLOTB, rg, cl, A); SBAR; }
            STEP(B, s + 1);
        }
        __syncthreads();
        cur ^= 1;
        oidx += (size_t)TOKB * 1024;
    }
}

// ---------------- post: y = o*sigmoid(gate); per-head RMS; *norm_w -> bf16
__global__ __launch_bounds__(128) void post_kernel(
    const float* __restrict__ ov, const float* __restrict__ gate,
    const float* __restrict__ normw, u16* __restrict__ ybf)
{
    const int gid = blockIdx.x;
    const int h = gid & 7;
    const int row = gid >> 3;
    const int tid = threadIdx.x;
    const int col = h * 128 + tid;

    __shared__ float red[128];

    const float o = ov[(size_t)row * 1024 + col];
    const float y = o * sigmf(gate[(size_t)row * 1024 + col]);

    red[tid] = y * y;
    __syncthreads();
    for (int off = 64; off > 0; off >>= 1) {
        if (tid < off) red[tid] += red[tid + off];
        __syncthreads();
    }
    const float rms = rsqrtf(red[0] * (1.f / 128.f) + 1e-6f);
    ybf[(size_t)row * 1024 + col] = f2bf(y * rms * normw[col]);
}

extern "C" void kernel_launch(void* const* d_in, const int* in_sizes, int n_in,
                              void* d_out, int out_size, void* d_ws, size_t ws_size,
                              hipStream_t stream)
{
    const float* x     = (const float*)d_in[0];
    const float* Wq    = (const float*)d_in[1];
    const float* Wk    = (const float*)d_in[2];
    const float* Wv    = (const float*)d_in[3];
    const float* Wf1   = (const float*)d_in[4];
    const float* Wf2   = (const float*)d_in[5];
    const float* Wbeta = (const float*)d_in[6];
    const float* Wog1  = (const float*)d_in[7];
    const float* Wog2  = (const float*)d_in[8];
    const float* normw = (const float*)d_in[9];
    const float* Wo    = (const float*)d_in[10];
    float* out = (float*)d_out;

    float* ws   = (float*)d_ws;
    float* qraw = ws;                                  // 4M f
    float* kraw = qraw + SZT;                          // 4M f (gate after prep)
    float* vraw = kraw + SZT;                          // 4M f (ybf after prep)
    float* sb   = vraw + SZT;                          // 17.04M f (early: xh/xl, wcat, f1og)
    float* ov   = sb + (size_t)32768 * RECF;           // 4M f (early: W splits; then fraw; then scan)
    float* wot  = ov + SZT;                            // 0.5M f
    float* wcatT= wot + 524288;                        // 0.25M f
    float* wfog = wcatT + 262144;                      // 0.25M f
    float* f1sp = wfog + 262144;                       // 1M f
    float* betap= f1sp + 1048576;                      // 32K f

    // overlapped (pre-prep) buffers inside sb
    u16*   xh   = (u16*)sb;                            // 4M u16
    u16*   xl   = xh + SZT;                            // 4M u16
    float* wcat = sb + SZT;                            // 0.26M f
    float* f1og = wcat + 262144;                       // 1M f

    // weight splits inside ov (dead before fraw written)
    u16* WqTh = (u16*)ov;
    u16* WqTl = WqTh + (size_t)1024 * 1024;
    u16* WkTh = WqTl + (size_t)1024 * 1024;
    u16* WkTl = WkTh + (size_t)1024 * 1024;
    u16* WvTh = WkTl + (size_t)1024 * 1024;
    u16* WvTl = WvTh + (size_t)1024 * 1024;
    float* fraw = ov;                                  // after q/k/v gemms

    u16* WoT    = (u16*)wot;
    u16* WcatTh = (u16*)wcatT;
    u16* WcatTl = WcatTh + (size_t)256 * 1024;
    u16* Wf2Th  = (u16*)wfog;
    u16* Wf2Tl  = Wf2Th + (size_t)1024 * 128;
    u16* Wog2Th = Wf2Tl + (size_t)1024 * 128;
    u16* Wog2Tl = Wog2Th + (size_t)1024 * 128;
    u16* f1ogh  = (u16*)f1sp;
    u16* f1ogl  = f1ogh + (size_t)4096 * 256;

    float* gate = kraw;
    u16*   ybf  = (u16*)vraw;

    dim3 b256(256), b128(128);

    wtrans_split_g<<<dim3(32, 32), b256, 0, stream>>>(Wq, WqTh, WqTl, 1024, 1024);
    wtrans_split_g<<<dim3(32, 32), b256, 0, stream>>>(Wk, WkTh, WkTl, 1024, 1024);
    wtrans_split_g<<<dim3(32, 32), b256, 0, stream>>>(Wv, WvTh, WvTl, 1024, 1024);
    wtrans<<<dim3(32, 32), b256, 0, stream>>>(Wo, WoT);
    conv_split<<<2048, b256, 0, stream>>>(x, xh, xl);
    wcat_kernel<<<1024, b256, 0, stream>>>(Wf1, Wog1, wcat);
    wtrans_split_g<<<dim3(8, 32), b256, 0, stream>>>(wcat, WcatTh, WcatTl, 1024, 256);
    wtrans_split_g<<<dim3(32, 4), b256, 0, stream>>>(Wf2, Wf2Th, Wf2Tl, 128, 1024);
    wtrans_split_g<<<dim3(32, 4), b256, 0, stream>>>(Wog2, Wog2Th, Wog2Tl, 128, 1024);
    beta_kernel<<<4096, b256, 0, stream>>>(x, Wbeta, betap);

    gemm_bf16_split<<<dim3(8, 32), b256, 0, stream>>>(xh, xl, WqTh, WqTl, qraw, 4096, 1024, 1024, 1024, 1024);
    gemm_bf16_split<<<dim3(8, 32), b256, 0, stream>>>(xh, xl, WkTh, WkTl, kraw, 4096, 1024, 1024, 1024, 1024);
    gemm_bf16_split<<<dim3(8, 32), b256, 0, stream>>>(xh, xl, WvTh, WvTl, vraw, 4096, 1024, 1024, 1024, 1024);
    gemm_bf16_split<<<dim3(2, 32), b256, 0, stream>>>(xh, xl, WcatTh, WcatTl, f1og, 4096, 256, 1024, 1024, 1024);
    conv_split<<<512, b256, 0, stream>>>(f1og, f1ogh, f1ogl);
    gemm_bf16_split<<<dim3(8, 32), b256, 0, stream>>>(f1ogh, f1ogl, Wf2Th, Wf2Tl, fraw, 4096, 1024, 128, 256, 128);

    prep_kernel<<<32768, b128, 0, stream>>>(qraw, kraw, vraw, fraw, betap, sb);
    gemm_bf16_split<<<dim3(8, 32), b256, 0, stream>>>(f1ogh + 128, f1ogl + 128, Wog2Th, Wog2Tl, gate, 4096, 1024, 128, 256, 128);
    scan_kernel<<<256, b256, 0, stream>>>(sb, ov);
    post_kernel<<<32768, b128, 0, stream>>>(ov, gate, normw, ybf);

    gemm_bf16<<<dim3(8, 32), b256, 0, stream>>>(ybf, WoT, out, 4096, 1024, 1024);
}

// Round 12
// 728.369 us; speedup vs baseline: 1.5562x; 1.1534x over previous
//
#include <hip/hip_runtime.h>
#include <cmath>

// DenseRnn on MI355X. B=2, N=2048, D=1024, H=8, HD=128.
//
//  wtrans_split_g: Wq/Wk/Wv (into one [3072][1024] block), Wcat, Wf2/Wog2
//    -> bf16 hi/lo transposed; Wo plain bf16
//  conv_split: x -> bf16 hi/lo; wcat: [Wf1|Wog1]
//  gemm_bf16_split: qkv = x@[Wq|Wk|Wv] (N=3072, one launch);
//    f1og = x@Wcat; fraw = f1@Wf2; gate = og1@Wog2
//  beta_kernel; prep -> records sb[520] = {k,e,qe,v, sc@512}
//  scan (CHUNKED, C=2): per-token update is affine in S with column-
//    independent linear part: S'[:,c] = A_t S[:,c] + v_c k_t,
//    o_t[c] = phi_t(S_prev[:,c]) + v_c d2. Chunk0 (t<1024) scans from 0 and
//    emits P0 = S_1024 (transposed). Chunk1 scans from 0 concurrently with
//    128 extra BASIS columns (S0=I, v=0) whose outputs r_t = T~^T phi_t.
//    Correction: o_t[c] += sum_j r_t[j] P0[j][c]  (per-stream MFMA GEMM).
//    768 blocks x 4 waves = 3072 waves = 3/SIMD (R11: 1/SIMD, stall-bound).
//  post: y = o*sigmoid(gate), per-head RMS, *norm_w -> bf16
//  gemm_bf16: y@Wo -> out

#define SZT ((size_t)4096 * 1024)
#define RECF 520
#define RECSTRIDE 4160     // 8*RECF floats between consecutive tokens of a stream
#define TOKB 16
#define SLOTB 1600         // k 512 | e 512 | qe 512 | v 32 | sc 16 | pad

typedef unsigned short u16;
typedef __attribute__((ext_vector_type(8))) short short8;
typedef __attribute__((ext_vector_type(4))) float f32x4;

__device__ __forceinline__ float sigmf(float x) { return 1.f / (1.f + expf(-x)); }
__device__ __forceinline__ float siluf(float x) { return x * sigmf(x); }
__device__ __forceinline__ u16 f2bf(float f) {
    unsigned int u = __float_as_uint(f);
    unsigned int r = (u + 0x7FFFu + ((u >> 16) & 1u)) >> 16;
    return (u16)r;
}
__device__ __forceinline__ float bf2f(u16 h) { return __uint_as_float((unsigned int)h << 16); }
__device__ __forceinline__ void splitbf(float f, u16& hi, u16& lo) {
    hi = f2bf(f);
    lo = f2bf(f - bf2f(hi));
}

#define GLOAD_LDS16(gp, lp) __builtin_amdgcn_global_load_lds( \
    (const __attribute__((address_space(1))) void*)(gp),      \
    (__attribute__((address_space(3))) void*)(lp), 16, 0, 0)

// ---------------- generic transpose+split: W [K][N] -> WTh/WTl [N][K]
__global__ __launch_bounds__(256) void wtrans_split_g(
    const float* __restrict__ W, u16* __restrict__ WTh, u16* __restrict__ WTl,
    int K, int N)
{
    __shared__ float t[32][33];
    const int tx = threadIdx.x & 31, ty = threadIdx.x >> 5;
    const int n0 = blockIdx.x * 32, k0 = blockIdx.y * 32;
#pragma unroll
    for (int i = 0; i < 4; i++)
        t[ty + i * 8][tx] = W[(size_t)(k0 + ty + i * 8) * N + n0 + tx];
    __syncthreads();
#pragma unroll
    for (int i = 0; i < 4; i++) {
        u16 hi, lo;
        splitbf(t[tx][ty + i * 8], hi, lo);
        WTh[(size_t)(n0 + ty + i * 8) * K + k0 + tx] = hi;
        WTl[(size_t)(n0 + ty + i * 8) * K + k0 + tx] = lo;
    }
}

// ---------------- plain transpose (Wo)
__global__ __launch_bounds__(256) void wtrans(const float* __restrict__ W, u16* __restrict__ WT)
{
    __shared__ float t[32][33];
    const int tx = threadIdx.x & 31, ty = threadIdx.x >> 5;
    const int n0 = blockIdx.x * 32, k0 = blockIdx.y * 32;
#pragma unroll
    for (int i = 0; i < 4; i++)
        t[ty + i * 8][tx] = W[(size_t)(k0 + ty + i * 8) * 1024 + n0 + tx];
    __syncthreads();
#pragma unroll
    for (int i = 0; i < 4; i++)
        WT[(size_t)(n0 + ty + i * 8) * 1024 + k0 + tx] = f2bf(t[tx][ty + i * 8]);
}

// ---------------- fp32 -> bf16 hi/lo elementwise (size = grid*256*8)
__global__ __launch_bounds__(256) void conv_split(
    const float* __restrict__ in, u16* __restrict__ oh, u16* __restrict__ ol)
{
    const size_t i = ((size_t)blockIdx.x * 256 + threadIdx.x) * 8;
    short8 rh, rl;
#pragma unroll
    for (int j = 0; j < 8; j++) {
        u16 hi, lo;
        splitbf(in[i + j], hi, lo);
        rh[j] = (short)hi; rl[j] = (short)lo;
    }
    *(short8*)&oh[i] = rh;
    *(short8*)&ol[i] = rl;
}

// ---------------- concat Wf1|Wog1 -> Wcat [1024][256]
__global__ __launch_bounds__(256) void wcat_kernel(
    const float* __restrict__ Wf1, const float* __restrict__ Wog1, float* __restrict__ Wcat)
{
    const int idx = blockIdx.x * 256 + threadIdx.x;
    const int k = idx >> 8, j = idx & 255;
    Wcat[idx] = (j < 128) ? Wf1[k * 128 + j] : Wog1[k * 128 + j - 128];
}

// ---------------- beta = 2*sigmoid(x @ Wbeta) ; one block per row
__global__ __launch_bounds__(256) void beta_kernel(
    const float* __restrict__ x, const float* __restrict__ Wbeta, float* __restrict__ beta)
{
    const int row = blockIdx.x;
    const int tid = threadIdx.x;
    const int lane = tid & 63, wid = tid >> 6;
    __shared__ float wsum[4][8];
    float4 xv = *(const float4*)&x[(size_t)row * 1024 + tid * 4];
    float p[8];
#pragma unroll
    for (int h = 0; h < 8; h++)
        p[h] = xv.x * Wbeta[(size_t)(tid * 4 + 0) * 8 + h]
             + xv.y * Wbeta[(size_t)(tid * 4 + 1) * 8 + h]
             + xv.z * Wbeta[(size_t)(tid * 4 + 2) * 8 + h]
             + xv.w * Wbeta[(size_t)(tid * 4 + 3) * 8 + h];
#pragma unroll
    for (int off = 32; off >= 1; off >>= 1)
#pragma unroll
        for (int h = 0; h < 8; h++) p[h] += __shfl_xor(p[h], off);
    if (lane == 0)
#pragma unroll
        for (int h = 0; h < 8; h++) wsum[wid][h] = p[h];
    __syncthreads();
    if (tid < 8) {
        float s = wsum[0][tid] + wsum[1][tid] + wsum[2][tid] + wsum[3][tid];
        beta[(size_t)row * 8 + tid] = 2.f * sigmf(s);
    }
}

// ---------------- split bf16 MFMA GEMM: C[M,N] = (Ah+Al)[lda] @ (BTh+BTl)[ldb]^T
__global__ __launch_bounds__(256) void gemm_bf16_split(
    const u16* __restrict__ Ah, const u16* __restrict__ Al,
    const u16* __restrict__ BTh, const u16* __restrict__ BTl,
    float* __restrict__ C, int M, int N, int K, int lda, int ldb)
{
    __shared__ u16 AsH[128 * 32];
    __shared__ u16 AsL[128 * 32];
    __shared__ u16 BsH[128 * 32];
    __shared__ u16 BsL[128 * 32];
    const int tid = threadIdx.x;
    const int lane = tid & 63;
    const int w = tid >> 6;
    const int wr = w >> 1, wc = w & 1;
    const int row0 = blockIdx.y * 128;
    const int col0 = blockIdx.x * 128;
    const int mrow = lane & 15;
    const int kgrp = (lane >> 4) * 8;

    f32x4 acc[4][4] = {};

    const int off0 = w * 1024 + lane * 16;
    const int r0 = off0 >> 6, kl0 = (off0 & 63) >> 1;
    const int off1 = off0 + 4096;
    const int r1 = off1 >> 6, kl1 = (off1 & 63) >> 1;

    for (int kt = 0; kt < K; kt += 32) {
        GLOAD_LDS16(Ah  + (size_t)(row0 + r0) * lda + kt + kl0, (char*)AsH + w * 1024);
        GLOAD_LDS16(Ah  + (size_t)(row0 + r1) * lda + kt + kl1, (char*)AsH + w * 1024 + 4096);
        GLOAD_LDS16(Al  + (size_t)(row0 + r0) * lda + kt + kl0, (char*)AsL + w * 1024);
        GLOAD_LDS16(Al  + (size_t)(row0 + r1) * lda + kt + kl1, (char*)AsL + w * 1024 + 4096);
        GLOAD_LDS16(BTh + (size_t)(col0 + r0) * ldb + kt + kl0, (char*)BsH + w * 1024);
        GLOAD_LDS16(BTh + (size_t)(col0 + r1) * ldb + kt + kl1, (char*)BsH + w * 1024 + 4096);
        GLOAD_LDS16(BTl + (size_t)(col0 + r0) * ldb + kt + kl0, (char*)BsL + w * 1024);
        GLOAD_LDS16(BTl + (size_t)(col0 + r1) * ldb + kt + kl1, (char*)BsL + w * 1024 + 4096);
        __syncthreads();

        short8 aH[4], aL[4], bH[4], bL[4];
#pragma unroll
        for (int mi = 0; mi < 4; ++mi) {
            aH[mi] = *(const short8*)&AsH[(wr * 64 + mi * 16 + mrow) * 32 + kgrp];
            aL[mi] = *(const short8*)&AsL[(wr * 64 + mi * 16 + mrow) * 32 + kgrp];
        }
#pragma unroll
        for (int ni = 0; ni < 4; ++ni) {
            bH[ni] = *(const short8*)&BsH[(wc * 64 + ni * 16 + mrow) * 32 + kgrp];
            bL[ni] = *(const short8*)&BsL[(wc * 64 + ni * 16 + mrow) * 32 + kgrp];
        }
#pragma unroll
        for (int mi = 0; mi < 4; ++mi)
#pragma unroll
            for (int ni = 0; ni < 4; ++ni) {
                acc[mi][ni] = __builtin_amdgcn_mfma_f32_16x16x32_bf16(aH[mi], bH[ni], acc[mi][ni], 0, 0, 0);
                acc[mi][ni] = __builtin_amdgcn_mfma_f32_16x16x32_bf16(aL[mi], bH[ni], acc[mi][ni], 0, 0, 0);
                acc[mi][ni] = __builtin_amdgcn_mfma_f32_16x16x32_bf16(aH[mi], bL[ni], acc[mi][ni], 0, 0, 0);
            }
        __syncthreads();
    }

    const int crow = (lane >> 4) * 4;
#pragma unroll
    for (int mi = 0; mi < 4; ++mi)
#pragma unroll
        for (int ni = 0; ni < 4; ++ni)
#pragma unroll
            for (int j = 0; j < 4; ++j)
                C[(size_t)(row0 + wr * 64 + mi * 16 + crow + j) * N + col0 + wc * 64 + ni * 16 + mrow]
                    = acc[mi][ni][j];
}

// ---------------- correction GEMM: per stream z, ov[t',col] += r[t',:] @ P0T[col,:]^T
// A = r hi/lo (lda=1024), BT = P0T hi/lo (ldb=128), M=1024, N-tile=128, K=128.
__global__ __launch_bounds__(256) void corr_gemm(
    const u16* __restrict__ Ah, const u16* __restrict__ Al,
    const u16* __restrict__ BTh, const u16* __restrict__ BTl,
    float* __restrict__ OV)
{
    __shared__ u16 AsH[128 * 32];
    __shared__ u16 AsL[128 * 32];
    __shared__ u16 BsH[128 * 32];
    __shared__ u16 BsL[128 * 32];
    const int tid = threadIdx.x;
    const int lane = tid & 63;
    const int w = tid >> 6;
    const int wr = w >> 1, wc = w & 1;
    const int row0 = blockIdx.y * 128;
    const int mrow = lane & 15;
    const int kgrp = (lane >> 4) * 8;

    const int bh = blockIdx.z;
    const int b = bh >> 3, h = bh & 7;
    const size_t aoff = (size_t)b * 2097152 + (size_t)h * 128;
    const size_t boff = (size_t)bh * 16384;
    const size_t coff = (size_t)b * 2097152 + (size_t)1048576 + (size_t)h * 128;

    f32x4 acc[4][4] = {};

    const int off0 = w * 1024 + lane * 16;
    const int r0 = off0 >> 6, kl0 = (off0 & 63) >> 1;
    const int off1 = off0 + 4096;
    const int r1 = off1 >> 6, kl1 = (off1 & 63) >> 1;

    for (int kt = 0; kt < 128; kt += 32) {
        GLOAD_LDS16(Ah  + aoff + (size_t)(row0 + r0) * 1024 + kt + kl0, (char*)AsH + w * 1024);
        GLOAD_LDS16(Ah  + aoff + (size_t)(row0 + r1) * 1024 + kt + kl1, (char*)AsH + w * 1024 + 4096);
        GLOAD_LDS16(Al  + aoff + (size_t)(row0 + r0) * 1024 + kt + kl0, (char*)AsL + w * 1024);
        GLOAD_LDS16(Al  + aoff + (size_t)(row0 + r1) * 1024 + kt + kl1, (char*)AsL + w * 1024 + 4096);
        GLOAD_LDS16(BTh + boff + (size_t)r0 * 128 + kt + kl0, (char*)BsH + w * 1024);
        GLOAD_LDS16(BTh + boff + (size_t)r1 * 128 + kt + kl1, (char*)BsH + w * 1024 + 4096);
        GLOAD_LDS16(BTl + boff + (size_t)r0 * 128 + kt + kl0, (char*)BsL + w * 1024);
        GLOAD_LDS16(BTl + boff + (size_t)r1 * 128 + kt + kl1, (char*)BsL + w * 1024 + 4096);
        __syncthreads();

        short8 aH[4], aL[4], bH[4], bL[4];
#pragma unroll
        for (int mi = 0; mi < 4; ++mi) {
            aH[mi] = *(const short8*)&AsH[(wr * 64 + mi * 16 + mrow) * 32 + kgrp];
            aL[mi] = *(const short8*)&AsL[(wr * 64 + mi * 16 + mrow) * 32 + kgrp];
        }
#pragma unroll
        for (int ni = 0; ni < 4; ++ni) {
            bH[ni] = *(const short8*)&BsH[(wc * 64 + ni * 16 + mrow) * 32 + kgrp];
            bL[ni] = *(const short8*)&BsL[(wc * 64 + ni * 16 + mrow) * 32 + kgrp];
        }
#pragma unroll
        for (int mi = 0; mi < 4; ++mi)
#pragma unroll
            for (int ni = 0; ni < 4; ++ni) {
                acc[mi][ni] = __builtin_amdgcn_mfma_f32_16x16x32_bf16(aH[mi], bH[ni], acc[mi][ni], 0, 0, 0);
                acc[mi][ni] = __builtin_amdgcn_mfma_f32_16x16x32_bf16(aL[mi], bH[ni], acc[mi][ni], 0, 0, 0);
                acc[mi][ni] = __builtin_amdgcn_mfma_f32_16x16x32_bf16(aH[mi], bL[ni], acc[mi][ni], 0, 0, 0);
            }
        __syncthreads();
    }

    const int crow = (lane >> 4) * 4;
    // col0 = 0; only wc*64 + ni*16 + mrow < 128 valid (always true: wc<2 -> max 127)
#pragma unroll
    for (int mi = 0; mi < 4; ++mi)
#pragma unroll
        for (int ni = 0; ni < 4; ++ni)
#pragma unroll
            for (int j = 0; j < 4; ++j) {
                const size_t idx = coff + (size_t)(row0 + wr * 64 + mi * 16 + crow + j) * 1024
                                 + wc * 64 + ni * 16 + mrow;
                OV[idx] += acc[mi][ni][j];
            }
}

// ---------------- plain bf16 MFMA GEMM (final projection)
__global__ __launch_bounds__(256) void gemm_bf16(
    const u16* __restrict__ A, const u16* __restrict__ BT, float* __restrict__ C,
    int M, int N, int K)
{
    __shared__ u16 As[128 * 32];
    __shared__ u16 Bs[128 * 32];
    const int tid = threadIdx.x;
    const int lane = tid & 63;
    const int w = tid >> 6;
    const int wr = w >> 1, wc = w & 1;
    const int row0 = blockIdx.y * 128;
    const int col0 = blockIdx.x * 128;
    const int mrow = lane & 15;
    const int kgrp = (lane >> 4) * 8;

    f32x4 acc[4][4] = {};

    const int off0 = w * 1024 + lane * 16;
    const int r0 = off0 >> 6, kl0 = (off0 & 63) >> 1;
    const int off1 = off0 + 4096;
    const int r1 = off1 >> 6, kl1 = (off1 & 63) >> 1;

    for (int kt = 0; kt < K; kt += 32) {
        GLOAD_LDS16(A  + (size_t)(row0 + r0) * K + kt + kl0, (char*)As + w * 1024);
        GLOAD_LDS16(A  + (size_t)(row0 + r1) * K + kt + kl1, (char*)As + w * 1024 + 4096);
        GLOAD_LDS16(BT + (size_t)(col0 + r0) * K + kt + kl0, (char*)Bs + w * 1024);
        GLOAD_LDS16(BT + (size_t)(col0 + r1) * K + kt + kl1, (char*)Bs + w * 1024 + 4096);
        __syncthreads();

        short8 aF[4], bF[4];
#pragma unroll
        for (int mi = 0; mi < 4; ++mi)
            aF[mi] = *(const short8*)&As[(wr * 64 + mi * 16 + mrow) * 32 + kgrp];
#pragma unroll
        for (int ni = 0; ni < 4; ++ni)
            bF[ni] = *(const short8*)&Bs[(wc * 64 + ni * 16 + mrow) * 32 + kgrp];
#pragma unroll
        for (int mi = 0; mi < 4; ++mi)
#pragma unroll
            for (int ni = 0; ni < 4; ++ni)
                acc[mi][ni] = __builtin_amdgcn_mfma_f32_16x16x32_bf16(aF[mi], bF[ni], acc[mi][ni], 0, 0, 0);
        __syncthreads();
    }

    const int crow = (lane >> 4) * 4;
#pragma unroll
    for (int mi = 0; mi < 4; ++mi)
#pragma unroll
        for (int ni = 0; ni < 4; ++ni)
#pragma unroll
            for (int j = 0; j < 4; ++j)
                C[(size_t)(row0 + wr * 64 + mi * 16 + crow + j) * N + col0 + wc * 64 + ni * 16 + mrow]
                    = acc[mi][ni][j];
}

// ---------------- prep: block per (row,h), 128 thr.
__global__ __launch_bounds__(128) void prep_kernel(
    const float* __restrict__ qkv, const float* __restrict__ fraw,
    const float* __restrict__ beta, float* __restrict__ sb)
{
    const int gid = blockIdx.x;
    const int h = gid & 7;
    const int row = gid >> 3;
    const int tid = threadIdx.x;
    const int col = h * 128 + tid;
    const size_t rb3 = (size_t)row * 3072;

    __shared__ float red[3][128];

    const float ksil = siluf(qkv[rb3 + 1024 + col]);
    red[0][tid] = ksil * ksil;
    __syncthreads();
    for (int off = 64; off > 0; off >>= 1) {
        if (tid < off) red[0][tid] += red[0][tid + off];
        __syncthreads();
    }
    const float rn = rsqrtf(red[0][0] + 1e-6f);
    __syncthreads();

    const float kn = ksil * rn;
    const float e  = sigmf(fraw[(size_t)row * 1024 + col]);
    const float qs = siluf(qkv[rb3 + col]);
    const float vs = siluf(qkv[rb3 + 2048 + col]);
    const float kev = e * kn;
    const float qev = e * qs;

    red[0][tid] = kev * kn;   // c
    red[1][tid] = qs * kev;   // d1
    red[2][tid] = qs * kn;    // d2
    __syncthreads();
    for (int off = 64; off > 0; off >>= 1) {
        if (tid < off) {
            red[0][tid] += red[0][tid + off];
            red[1][tid] += red[1][tid + off];
            red[2][tid] += red[2][tid + off];
        }
        __syncthreads();
    }

    float* o = sb + (size_t)gid * RECF;
    o[tid]        = kn;
    o[128 + tid]  = e;
    o[256 + tid]  = qev;
    o[384 + tid]  = vs;
    if (tid == 0) {
        o[512] = beta[(size_t)row * 8 + h];
        o[513] = red[0][0];
        o[514] = red[1][0];
        o[515] = red[2][0];
    }
}

// ---------------- scan
// 32-lane sum: 4 DPP stages (within 16) + ds_swizzle xor16 (within 32-groups).
__device__ __forceinline__ float red32(float x)
{
    x += __int_as_float(__builtin_amdgcn_mov_dpp(__float_as_int(x), 0xB1,  0xF, 0xF, true));
    x += __int_as_float(__builtin_amdgcn_mov_dpp(__float_as_int(x), 0x4E,  0xF, 0xF, true));
    x += __int_as_float(__builtin_amdgcn_mov_dpp(__float_as_int(x), 0x141, 0xF, 0xF, true));
    x += __int_as_float(__builtin_amdgcn_mov_dpp(__float_as_int(x), 0x140, 0xF, 0xF, true));
    x += __int_as_float(__builtin_amdgcn_ds_swizzle(__float_as_int(x), 0x401F));
    return x;
}

struct TR { float4 k, e, q, sc; float vc; };

__device__ __forceinline__ void ldtok(const char* __restrict__ rec, int rg, int cl, TR& T)
{
    T.k  = *(const float4*)(rec + rg * 16);
    T.e  = *(const float4*)(rec + 512 + rg * 16);
    T.q  = *(const float4*)(rec + 1024 + rg * 16);
    T.vc = *(const float*)(rec + 1536 + cl * 4);
    T.sc = *(const float4*)(rec + 1568);
}

#define STEP(T, SOFF)                                                              \
  {                                                                                \
    const float m0 = T.k.x * S0, m1 = T.k.y * S1, m2 = T.k.z * S2, m3 = T.k.w * S3; \
    float bS  = (m0 + m1) + (m2 + m3);                                             \
    float keS = (T.e.x * m0 + T.e.y * m1) + (T.e.z * m2 + T.e.w * m3);             \
    float qeS = (T.q.x * S0 + T.q.y * S1) + (T.q.z * S2 + T.q.w * S3);             \
    bS = red32(bS); keS = red32(keS); qeS = red32(qeS);                            \
    const float bSb = T.sc.x * bS;                                                 \
    const float ks  = keS - bSb * T.sc.y;                                          \
    const float wv  = T.vc - T.sc.x * ks;                                          \
    const float o   = (qeS - bSb * T.sc.z) + wv * T.sc.w;                          \
    S0 = T.e.x * (S0 - bSb * T.k.x) + wv * T.k.x;                                  \
    S1 = T.e.y * (S1 - bSb * T.k.y) + wv * T.k.y;                                  \
    S2 = T.e.z * (S2 - bSb * T.k.z) + wv * T.k.z;                                  \
    S3 = T.e.w * (S3 - bSb * T.k.w) + wv * T.k.w;                                  \
    if (rg == 0) outp[oidx + (size_t)(SOFF) * 1024] = o;                           \
  }

#define SBAR __builtin_amdgcn_sched_barrier(0)

__device__ __forceinline__ void stage_batch(
    const float* __restrict__ p0, char* ldsbuf, int t0, int w, int lane, int vg)
{
    for (int s = w; s < TOKB; s += 4) {
        const char* src = (const char*)(p0 + (size_t)(t0 + s) * RECSTRIDE);
        char* dst = ldsbuf + s * SLOTB;
        GLOAD_LDS16(src + lane * 16, dst);                               // k,e (1024B)
        if (lane < 32) GLOAD_LDS16(src + 1024 + lane * 16, dst + 1024);  // qe (512B)
        if (lane < 2)  GLOAD_LDS16(src + 1536 + vg * 32 + lane * 16, dst + 1536); // v slice
        if (lane == 0) GLOAD_LDS16(src + 2048, dst + 1568);              // sc
    }
}

// 768 blocks x 256 threads (3072 waves = 3/SIMD, 3 blocks/CU at 50KB LDS).
// blk<256: chunk0 (t 0..1023), 128 real cols, emits P0^T at end.
// blk>=256: chunk1 (t 1024..2047): cols 0..127 real (from S=0, corrected later),
//           cols 128..255 basis (S0=I, v=0) -> r_t to rbuf.
__global__ __launch_bounds__(256) void scan_kernel(
    const float* __restrict__ sb, float* __restrict__ ov,
    float* __restrict__ rbuf, float* __restrict__ pbufT)
{
    __shared__ char lds[2 * TOKB * SLOTB];   // 51200 B

    const int tid = threadIdx.x;
    const int blk = blockIdx.x;
    const int cl = tid >> 5;
    const int rg = tid & 31;
    const int w = tid >> 6;
    const int lane = tid & 63;

    int bh, vg, tstart, colx;
    bool chunk0, basis = false;
    if (blk < 256) {
        bh = blk & 15; const int cg = blk >> 4;
        colx = cg * 8 + cl; vg = cg; tstart = 0; chunk0 = true;
    } else {
        const int bi = blk - 256;
        bh = bi & 15; const int cg2 = bi >> 4;
        colx = cg2 * 8 + cl; vg = cg2 & 15; tstart = 1024; chunk0 = false;
        basis = colx >= 128;
    }
    const int b = bh >> 3, h = bh & 7;
    const size_t base = (size_t)b * 2048 * 8 + h;
    const float* p0 = sb + base * RECF + (size_t)tstart * RECSTRIDE;

    float* outp;
    size_t oidx;
    if (chunk0)      { outp = ov;   oidx = base * 128 + colx; }
    else if (!basis) { outp = ov;   oidx = base * 128 + (size_t)1048576 + colx; }
    else             { outp = rbuf; oidx = base * 128 + (colx - 128); }

    const float vmask = basis ? 0.f : 1.f;
    float S0, S1, S2, S3;
    if (basis) {
        const int jb = colx - 128;
        S0 = (rg * 4 + 0 == jb) ? 1.f : 0.f;
        S1 = (rg * 4 + 1 == jb) ? 1.f : 0.f;
        S2 = (rg * 4 + 2 == jb) ? 1.f : 0.f;
        S3 = (rg * 4 + 3 == jb) ? 1.f : 0.f;
    } else { S0 = S1 = S2 = S3 = 0.f; }

    stage_batch(p0, lds, 0, w, lane, vg);
    __syncthreads();

    int cur = 0;
    for (int t0 = 0; t0 < 1024; t0 += TOKB) {
        if (t0 + TOKB < 1024)
            stage_batch(p0, lds + (cur ^ 1) * (TOKB * SLOTB), t0 + TOKB, w, lane, vg);

        const char* bufp = lds + cur * (TOKB * SLOTB);
        TR A, B;
        ldtok(bufp, rg, cl, A); A.vc *= vmask; SBAR;
#pragma unroll
        for (int s = 0; s < TOKB; s += 2) {
            ldtok(bufp + (s + 1) * SLOTB, rg, cl, B); B.vc *= vmask; SBAR;
            STEP(A, s);
            if (s + 2 < TOKB) { ldtok(bufp + (s + 2) * SLOTB, rg, cl, A); A.vc *= vmask; SBAR; }
            STEP(B, s + 1);
        }
        __syncthreads();
        cur ^= 1;
        oidx += (size_t)TOKB * 1024;
    }

    if (chunk0) {
        float* pT = pbufT + (size_t)bh * 16384 + (size_t)colx * 128 + rg * 4;
        pT[0] = S0; pT[1] = S1; pT[2] = S2; pT[3] = S3;
    }
}

// ---------------- post: y = o*sigmoid(gate); per-head RMS; *norm_w -> bf16
__global__ __launch_bounds__(128) void post_kernel(
    const float* __restrict__ ov, const float* __restrict__ gate,
    const float* __restrict__ normw, u16* __restrict__ ybf)
{
    const int gid = blockIdx.x;
    const int h = gid & 7;
    const int row = gid >> 3;
    const int tid = threadIdx.x;
    const int col = h * 128 + tid;

    __shared__ float red[128];

    const float o = ov[(size_t)row * 1024 + col];
    const float y = o * sigmf(gate[(size_t)row * 1024 + col]);

    red[tid] = y * y;
    __syncthreads();
    for (int off = 64; off > 0; off >>= 1) {
        if (tid < off) red[tid] += red[tid + off];
        __syncthreads();
    }
    const float rms = rsqrtf(red[0] * (1.f / 128.f) + 1e-6f);
    ybf[(size_t)row * 1024 + col] = f2bf(y * rms * normw[col]);
}

extern "C" void kernel_launch(void* const* d_in, const int* in_sizes, int n_in,
                              void* d_out, int out_size, void* d_ws, size_t ws_size,
                              hipStream_t stream)
{
    const float* x     = (const float*)d_in[0];
    const float* Wq    = (const float*)d_in[1];
    const float* Wk    = (const float*)d_in[2];
    const float* Wv    = (const float*)d_in[3];
    const float* Wf1   = (const float*)d_in[4];
    const float* Wf2   = (const float*)d_in[5];
    const float* Wbeta = (const float*)d_in[6];
    const float* Wog1  = (const float*)d_in[7];
    const float* Wog2  = (const float*)d_in[8];
    const float* normw = (const float*)d_in[9];
    const float* Wo    = (const float*)d_in[10];
    float* out = (float*)d_out;

    float* ws    = (float*)d_ws;
    float* qkv   = ws;                                 // 12M f [4096x3072]
    float* sb    = qkv + 3 * SZT;                      // 17.04M f
    float* ovr   = sb + (size_t)32768 * RECF;          // 4M f (early: Wqkv splits; then fraw; then ov)
    float* rbuf  = ovr + SZT;                          // 4M f
    float* pbufT = rbuf + SZT;                         // 256K f
    float* wot   = pbufT + 262144;                     // 0.5M f
    float* wcatT = wot + 524288;                       // 0.25M f
    float* wfog  = wcatT + 262144;                     // 0.25M f
    float* f1sp  = wfog + 262144;                      // 1M f
    float* betap = f1sp + 1048576;                     // 32K f
    float* psp   = betap + 32768;                      // 0.25M f
    float* xsp   = psp + 262144;                       // 4M f (xh/xl; later rbh/rbl)

    // early buffers inside sb (dead before prep writes sb)
    float* wcat = sb;                                  // 0.26M f
    float* f1og = wcat + 262144;                       // 1M f

    u16* WqkvTh = (u16*)ovr;                           // 3M u16
    u16* WqkvTl = WqkvTh + (size_t)3 * 1024 * 1024;    // 3M u16 (total 12MB <= 16MB)
    float* fraw = ovr;                                 // after qkv gemm

    u16* xh  = (u16*)xsp;
    u16* xl  = xh + SZT;
    u16* rbh = (u16*)xsp;                              // after x splits dead
    u16* rbl = rbh + SZT;

    u16* WoT    = (u16*)wot;
    u16* WcatTh = (u16*)wcatT;
    u16* WcatTl = WcatTh + (size_t)256 * 1024;
    u16* Wf2Th  = (u16*)wfog;
    u16* Wf2Tl  = Wf2Th + (size_t)1024 * 128;
    u16* Wog2Th = Wf2Tl + (size_t)1024 * 128;
    u16* Wog2Tl = Wog2Th + (size_t)1024 * 128;
    u16* f1ogh  = (u16*)f1sp;
    u16* f1ogl  = f1ogh + (size_t)4096 * 256;
    u16* pTh    = (u16*)psp;
    u16* pTl    = pTh + 262144;

    float* gate = qkv;                                 // qkv dead after prep
    u16*   ybf  = (u16*)(qkv + SZT);

    dim3 b256(256), b128(128);

    wtrans_split_g<<<dim3(32, 32), b256, 0, stream>>>(Wq, WqkvTh, WqkvTl, 1024, 1024);
    wtrans_split_g<<<dim3(32, 32), b256, 0, stream>>>(Wk, WqkvTh + (size_t)1024 * 1024, WqkvTl + (size_t)1024 * 1024, 1024, 1024);
    wtrans_split_g<<<dim3(32, 32), b256, 0, stream>>>(Wv, WqkvTh + (size_t)2048 * 1024, WqkvTl + (size_t)2048 * 1024, 1024, 1024);
    wtrans<<<dim3(32, 32), b256, 0, stream>>>(Wo, WoT);
    conv_split<<<2048, b256, 0, stream>>>(x, xh, xl);
    wcat_kernel<<<1024, b256, 0, stream>>>(Wf1, Wog1, wcat);
    wtrans_split_g<<<dim3(8, 32), b256, 0, stream>>>(wcat, WcatTh, WcatTl, 1024, 256);
    wtrans_split_g<<<dim3(32, 4), b256, 0, stream>>>(Wf2, Wf2Th, Wf2Tl, 128, 1024);
    wtrans_split_g<<<dim3(32, 4), b256, 0, stream>>>(Wog2, Wog2Th, Wog2Tl, 128, 1024);
    beta_kernel<<<4096, b256, 0, stream>>>(x, Wbeta, betap);

    gemm_bf16_split<<<dim3(24, 32), b256, 0, stream>>>(xh, xl, WqkvTh, WqkvTl, qkv, 4096, 3072, 1024, 1024, 1024);
    gemm_bf16_split<<<dim3(2, 32), b256, 0, stream>>>(xh, xl, WcatTh, WcatTl, f1og, 4096, 256, 1024, 1024, 1024);
    conv_split<<<512, b256, 0, stream>>>(f1og, f1ogh, f1ogl);
    gemm_bf16_split<<<dim3(8, 32), b256, 0, stream>>>(f1ogh, f1ogl, Wf2Th, Wf2Tl, fraw, 4096, 1024, 128, 256, 128);

    prep_kernel<<<32768, b128, 0, stream>>>(qkv, fraw, betap, sb);
    gemm_bf16_split<<<dim3(8, 32), b256, 0, stream>>>(f1ogh + 128, f1ogl + 128, Wog2Th, Wog2Tl, gate, 4096, 1024, 128, 256, 128);

    scan_kernel<<<768, b256, 0, stream>>>(sb, ovr, rbuf, pbufT);

    conv_split<<<2048, b256, 0, stream>>>(rbuf, rbh, rbl);
    conv_split<<<128, b256, 0, stream>>>(pbufT, pTh, pTl);
    corr_gemm<<<dim3(1, 8, 16), b256, 0, stream>>>(rbh, rbl, pTh, pTl, ovr);

    post_kernel<<<32768, b128, 0, stream>>>(ovr, gate, normw, ybf);

    gemm_bf16<<<dim3(8, 32), b256, 0, stream>>>(ybf, WoT, out, 4096, 1024, 1024);
}